// Round 10
// baseline (834.962 us; speedup 1.0000x reference)
//
#include <hip/hip_runtime.h>
#include <hip/hip_bf16.h>
#include <stdint.h>

// Problem constants (match setup_inputs)
#define M_ROWS 100352   // 2048 * 49
#define C_DIM  512
#define QKV_N  1536
#define NH     16
#define HD     32
#define NWIN   49       // window tokens (7*7)
#define NMASK  64

typedef __attribute__((ext_vector_type(4))) float        f32x4;
typedef __attribute__((ext_vector_type(8))) short        bf16x8;
typedef __attribute__((ext_vector_type(4))) unsigned int u32x4;

static __device__ __forceinline__ unsigned short f32_to_bf16(float f) {
  union { float f; unsigned int u; } v; v.f = f;
  unsigned int u = v.u;
  return (unsigned short)((u + 0x7FFFu + ((u >> 16) & 1u)) >> 16);  // RNE
}

// global -> LDS direct DMA, 16B per lane. dest = wave-uniform base + lane*16.
static __device__ __forceinline__ void gload_lds16(const void* g, void* l) {
  __builtin_amdgcn_global_load_lds(
      (const __attribute__((address_space(1))) unsigned int*)g,
      (__attribute__((address_space(3))) unsigned int*)l, 16, 0, 0);
}

// ---------------------------------------------------------------- k_cvt
__global__ void k_cvt(const float* __restrict__ in, unsigned short* __restrict__ out, int n4) {
  int i = blockIdx.x * blockDim.x + threadIdx.x;
  int stride = gridDim.x * blockDim.x;
  for (; i < n4; i += stride) {
    float4 v = ((const float4*)in)[i];
    ushort4 o = make_ushort4(f32_to_bf16(v.x), f32_to_bf16(v.y),
                             f32_to_bf16(v.z), f32_to_bf16(v.w));
    ((ushort4*)out)[i] = o;
  }
}

// ---------------------- transpose + convert weights -> B-FRAG layout
// in: K x N f32 (row-major).  Output = B^T (N x K) in 16x16x32-MFMA frag
// chunk layout: chunk(nc = n>>4, kc = k>>5) is 64 lanes x 16B contiguous;
// within chunk, lane = (n&15) + 16*((k>>3)&3), byte = (k&7)*2.  A GEMM wave
// loads one chunk with a single coalesced global_load_dwordx4 (lane*8
// ushorts) and feeds it straight to the MFMA A-operand slot.
__global__ void k_transpose_cvt_frag(const float* __restrict__ in,
                                     unsigned short* __restrict__ out,
                                     int K, int N) {
  __shared__ float t[32][33];
  const int n0 = blockIdx.x * 32, k0 = blockIdx.y * 32;
  const int tx = threadIdx.x & 31, ty = threadIdx.x >> 5;  // 32 x 8
#pragma unroll
  for (int rr = 0; rr < 32; rr += 8)
    t[ty + rr][tx] = in[(size_t)(k0 + ty + rr) * N + n0 + tx];
  __syncthreads();
#pragma unroll
  for (int rr = 0; rr < 32; rr += 8) {
    const int n = n0 + ty + rr, k = k0 + tx;
    const size_t addr = ((size_t)(n >> 4) * (K >> 5) + (k >> 5)) * 512 +
                        ((n & 15) + 16 * ((k >> 3) & 3)) * 8 + (k & 7);
    out[addr] = f32_to_bf16(t[tx][ty + rr]);
  }
}

// ----------------------------------------- fused bias+mask table (padded)
// bmt[w][h][i][j] (64x16x64x64 f32) = mask[w][i][j] + bias[h][i][j], -1e30 pad.
__global__ __launch_bounds__(256) void k_bm(const float* __restrict__ mask,
                                            const float* __restrict__ rel,
                                            float* __restrict__ bmt) {
  const int idx = blockIdx.x * 256 + threadIdx.x;   // w<<16 | h<<12 | i<<6 | j
  const int j = idx & 63, i = (idx >> 6) & 63, h = (idx >> 12) & 15, w = idx >> 16;
  float v = -1e30f;
  if (i < NWIN && j < NWIN) {
    const int rpi = ((j / 7) - (i / 7) + 6) * 13;
    v = mask[w * (NWIN * NWIN) + i * NWIN + j] + rel[rpi * NH + h];
  }
  bmt[idx] = v;
}

// ------------------------------------------------------ GEMM (hybrid)
// C[M,N] = A[M,512](bf16 row-major) * Bf^T + bias[N], Bf in frag layout.
// BM=BN=128, BK=64, 4 waves (2x2), 64x64/wave.  A: global_load_lds into
// conflict-free subtile layout ([cg4][row16][8col] per 16x32 subtile; 0
// conflicts measured r4-r8), double-buffered 2x16KB.  B: 8x16B frag chunks
// per tile per wave straight from L2 (B <= 1.5 MB, L2-resident; r9 proved
// the coalesced frag path).  LDS traffic/tile = 16KB write + 32KB read
// (~375 cyc) ~ balanced vs 310 cyc MFMA — the r5 LDS wall (192KB/tile) is
// the thing this removes.  ~125 VGPR + 32KB LDS -> 4 blocks/CU: cross-block
// overlap absorbs the __syncthreads drains (m97/m114 mechanism) — so plain
// syncthreads, no inline asm, compiler manages all waits.
// Single barrier per tile is sufficient: reads of tile t-1 precede pub(t)
// in program order; writes of tile t+1 are issued after pub(t).
// SWAPPED mfma operands (verified r6): acc = mfma(b, a, acc) -> lane holds
// rows m = 16mi+lr, cols n = 16nj+4lg+{0..3} -> packed 8B/16B C-stores.
template <int OUT_BF16>
__global__ __launch_bounds__(256, 4) void k_gemmh(const unsigned short* __restrict__ A,
                                                  const unsigned short* __restrict__ Bf,
                                                  const float* __restrict__ bias,
                                                  void* __restrict__ Cout,
                                                  int M, int N) {
  __shared__ __align__(16) unsigned short lds[2][8192];  // A only: 2 x 16KB
  const int tid = threadIdx.x;
  const int lane = tid & 63, wave = tid >> 6;
  const int wr = wave >> 1, wc = wave & 1;
  const int lr = lane & 15, lg = lane >> 4;

  // bijective XCD swizzle (grid %8==0); bx fastest -> same-XCD neighbors
  // share the A panel (L2 reuse).
  const int nwg = gridDim.x, q8 = nwg >> 3;
  const int wg = (blockIdx.x & 7) * q8 + (blockIdx.x >> 3);
  const int gx = N >> 7;
  const int bx = wg % gx, by = wg / gx;
  const int m0 = by << 7, n0 = bx << 7;

  const int srow = lane & 15;          // staging: row within row-group
  const int scol = (lane >> 4) * 8;    // staging: col within 32-col group

  const f32x4 fz = {0.f, 0.f, 0.f, 0.f};
  f32x4 acc[4][4];
#pragma unroll
  for (int i = 0; i < 4; ++i)
#pragma unroll
    for (int j = 0; j < 4; ++j) acc[i][j] = fz;

  // A staging: 16 subtiles (s = rg*2 + cg32), wave stages s = wave*4 + i.
  auto stage = [&](int t, int buf) {
    const int k0 = t << 6;
#pragma unroll
    for (int i = 0; i < 4; ++i) {
      const int s = wave * 4 + i;
      const int rg = s >> 1, cg32 = s & 1;
      gload_lds16(A + (size_t)(m0 + rg * 16 + srow) * C_DIM + k0 + cg32 * 32 + scol,
                  &lds[buf][s * 512]);
    }
  };

  const int roff = lg * 128 + lr * 8;          // ushort offset within subtile
  const int ncb = (n0 >> 4) + wc * 4;          // B chunk row base
  const int KC = C_DIM >> 5;                   // 16 k-chunks

  stage(0, 0);
  for (int t = 0; t < 8; ++t) {
    const int cur = t & 1;
    __syncthreads();                   // publishes tile-t stages (vmcnt drained)
    if (t < 7) stage(t + 1, cur ^ 1);  // next tile into other buffer

    // B frag chunks for this tile: 8 coalesced 16B loads from L2
    bf16x8 b_[4][2];
#pragma unroll
    for (int nj = 0; nj < 4; ++nj)
#pragma unroll
      for (int ks = 0; ks < 2; ++ks)
        b_[nj][ks] = *(const bf16x8*)(Bf + ((size_t)(ncb + nj) * KC + 2 * t + ks) * 512 + lane * 8);

    const unsigned short* la = lds[cur];
#pragma unroll
    for (int ks = 0; ks < 2; ++ks) {
      bf16x8 a_[4];
#pragma unroll
      for (int mi = 0; mi < 4; ++mi)
        a_[mi] = *(const bf16x8*)(la + (((wr * 4 + mi) * 2 + ks) * 512) + roff);
#pragma unroll
      for (int mi = 0; mi < 4; ++mi)
#pragma unroll
        for (int nj = 0; nj < 4; ++nj)
          acc[mi][nj] = __builtin_amdgcn_mfma_f32_16x16x32_bf16(b_[nj][ks], a_[mi], acc[mi][nj], 0, 0, 0);
    }
  }

  // epilogue: lane holds rows m = 16mi+lr, cols n = 16nj+4lg+{0..3}
  f32x4 b4[4];
#pragma unroll
  for (int nj = 0; nj < 4; ++nj)
    b4[nj] = *(const f32x4*)(bias + n0 + wc * 64 + nj * 16 + 4 * lg);
#pragma unroll
  for (int mi = 0; mi < 4; ++mi) {
    const size_t row = (size_t)(m0 + wr * 64 + mi * 16 + lr);
#pragma unroll
    for (int nj = 0; nj < 4; ++nj) {
      const int colbase = n0 + wc * 64 + nj * 16 + 4 * lg;
      float v0 = acc[mi][nj][0] + b4[nj][0];
      float v1 = acc[mi][nj][1] + b4[nj][1];
      float v2 = acc[mi][nj][2] + b4[nj][2];
      float v3 = acc[mi][nj][3] + b4[nj][3];
      if (OUT_BF16) {
        uint2 st;
        st.x = (unsigned int)f32_to_bf16(v0) | ((unsigned int)f32_to_bf16(v1) << 16);
        st.y = (unsigned int)f32_to_bf16(v2) | ((unsigned int)f32_to_bf16(v3) << 16);
        *(uint2*)((unsigned short*)Cout + row * N + colbase) = st;
      } else {
        f32x4 st = {v0, v1, v2, v3};
        *(f32x4*)((float*)Cout + row * N + colbase) = st;
      }
    }
  }
}

// ------------------------------------------------------------- attention
// 4 waves/block, one (b,h) per wave, zero barriers (waves independent).
__global__ __launch_bounds__(256) void k_attn(const unsigned short* __restrict__ qkv,
                                              const float* __restrict__ bmt,
                                              unsigned short* __restrict__ aout) {
  const int wave = threadIdx.x >> 6, lane = threadIdx.x & 63;
  const int lr = lane & 15, lg = lane >> 4;
  const int idx = blockIdx.x * 4 + wave;
  const int b = idx >> 4, h = idx & 15, w = b & 63;

  __shared__ __align__(16) unsigned short Pl[4][2048];  // [32 rows][64] swizzled
  __shared__ __align__(16) unsigned short Vt[4][2112];  // V^T, stride 66
  unsigned short* pl = Pl[wave];
  unsigned short* vt = Vt[wave];

  const unsigned short* qp = qkv + (size_t)b * NWIN * QKV_N + h * HD;
  const unsigned short* kp = qp + C_DIM;
  const unsigned short* vp = qp + 2 * C_DIM;

  bf16x8 kf[4], qf[4];
#pragma unroll
  for (int t = 0; t < 4; ++t) {
    kf[t] = *(const bf16x8*)(kp + (size_t)(t * 16 + lr) * QKV_N + lg * 8);
    qf[t] = *(const bf16x8*)(qp + (size_t)(t * 16 + lr) * QKV_N + lg * 8);
  }

  const u32x4 zv = {0u, 0u, 0u, 0u};
#pragma unroll
  for (int c0 = 0; c0 < 4; ++c0) {
    const int c = c0 * 64 + lane;
    const int key = c >> 2, d0 = (c & 3) << 3;
    union { u32x4 v; unsigned short s[8]; } tmp;
    tmp.v = (key < NWIN) ? *(const u32x4*)(vp + (size_t)key * QKV_N + d0) : zv;
#pragma unroll
    for (int jj = 0; jj < 8; ++jj) vt[(d0 + jj) * 66 + key] = tmp.s[jj];
  }

  const f32x4 fz = {0.f, 0.f, 0.f, 0.f};
  f32x4 s[4][4];  // [mi = j-frag][ni = i-frag]
#pragma unroll
  for (int mi = 0; mi < 4; ++mi)
#pragma unroll
    for (int ni = 0; ni < 4; ++ni) s[mi][ni] = fz;
#pragma unroll
  for (int mi = 0; mi < 4; ++mi)
#pragma unroll
    for (int ni = 0; ni < 4; ++ni)
      s[mi][ni] = __builtin_amdgcn_mfma_f32_16x16x32_bf16(kf[mi], qf[ni], s[mi][ni], 0, 0, 0);

  union VU { unsigned int u[4]; bf16x8 v; };
  VU vfr[2][2];  // [nj][ks]
#pragma unroll
  for (int nj = 0; nj < 2; ++nj)
#pragma unroll
    for (int ks = 0; ks < 2; ++ks) {
      const int base = ((16 * nj + lr) * 66 + 32 * ks + 8 * lg) >> 1;
#pragma unroll
      for (int u = 0; u < 4; ++u) vfr[nj][ks].u[u] = ((const unsigned int*)vt)[base + u];
    }

  const float scale = 0.1767766952966369f;  // 32^-0.5
  const float* tbl = bmt + ((size_t)(w * NH + h) << 12);

  f32x4 o[4][2];
#pragma unroll
  for (int qi = 0; qi < 4; ++qi)
#pragma unroll
    for (int nj = 0; nj < 2; ++nj) o[qi][nj] = fz;

#pragma unroll
  for (int ni = 0; ni < 4; ++ni) {
    float v[16];
    float mx = -3e38f;
#pragma unroll
    for (int mi = 0; mi < 4; ++mi) {
      const f32x4 t4 = *(const f32x4*)(tbl + (16 * ni + lr) * 64 + 16 * mi + 4 * lg);
#pragma unroll
      for (int r = 0; r < 4; ++r) {
        v[mi * 4 + r] = fmaf(s[mi][ni][r], scale, t4[r]);
        mx = fmaxf(mx, v[mi * 4 + r]);
      }
    }
    mx = fmaxf(mx, __shfl_xor(mx, 16));
    mx = fmaxf(mx, __shfl_xor(mx, 32));
    float sum = 0.f;
#pragma unroll
    for (int t = 0; t < 16; ++t) {
      v[t] = __expf(v[t] - mx);
      sum += v[t];
    }
    sum += __shfl_xor(sum, 16);
    sum += __shfl_xor(sum, 32);
    const float inv = __builtin_amdgcn_rcpf(sum);

    const int ip = 16 * (ni & 1) + lr;
#pragma unroll
    for (int mi = 0; mi < 4; ++mi) {
      const unsigned int lo = (unsigned int)f32_to_bf16(v[mi * 4 + 0] * inv) |
                              ((unsigned int)f32_to_bf16(v[mi * 4 + 1] * inv) << 16);
      const unsigned int hi = (unsigned int)f32_to_bf16(v[mi * 4 + 2] * inv) |
                              ((unsigned int)f32_to_bf16(v[mi * 4 + 3] * inv) << 16);
      const int byteoff = 32 * mi + 8 * lg;
      const int sw = byteoff ^ ((ip & 7) << 4);
      uint2 w2; w2.x = lo; w2.y = hi;
      *(uint2*)((char*)pl + ip * 128 + sw) = w2;
    }

    if (ni & 1) {
      asm volatile("s_waitcnt lgkmcnt(0)" ::: "memory");
      __builtin_amdgcn_sched_barrier(0);
      const int half = ni >> 1;
#pragma unroll
      for (int q2 = 0; q2 < 2; ++q2) {
        const int qi = half * 2 + q2;
        const int ipr = 16 * q2 + lr;
#pragma unroll
        for (int ks = 0; ks < 2; ++ks) {
          const int bo = 64 * ks + 16 * lg;
          const int swr = bo ^ ((ipr & 7) << 4);
          const bf16x8 pa = *(const bf16x8*)((const char*)pl + ipr * 128 + swr);
#pragma unroll
          for (int nj = 0; nj < 2; ++nj)
            o[qi][nj] = __builtin_amdgcn_mfma_f32_16x16x32_bf16(pa, vfr[nj][ks].v, o[qi][nj], 0, 0, 0);
        }
      }
    }
  }

  const size_t orow = (size_t)b * NWIN;
#pragma unroll
  for (int qi = 0; qi < 4; ++qi)
#pragma unroll
    for (int r = 0; r < 4; ++r) {
      const int i = 16 * qi + 4 * lg + r;
      if (i < NWIN) {
#pragma unroll
        for (int nj = 0; nj < 2; ++nj)
          aout[(orow + i) * C_DIM + h * HD + 16 * nj + lr] = f32_to_bf16(o[qi][nj][r]);
      }
    }
}

// ---------------------------------------------------------------- launch
static const size_t SZ_QKV = (size_t)M_ROWS * QKV_N * 2;   // 308 MB
static const size_t SZ_XB  = (size_t)M_ROWS * C_DIM * 2;   // 103 MB
static const size_t SZ_WQ  = (size_t)QKV_N * C_DIM * 2;    // 1.5 MB
static const size_t OFF_QKV = 0;
static const size_t OFF_XB  = OFF_QKV + SZ_QKV;   // x_bf16, later attn_out
static const size_t OFF_WQF = OFF_XB + SZ_XB;     // qkv_w B^T frag
static const size_t OFF_WPF = OFF_WQF + SZ_WQ;    // proj_w B^T frag

extern "C" void kernel_launch(void* const* d_in, const int* in_sizes, int n_in,
                              void* d_out, int out_size, void* d_ws, size_t ws_size,
                              hipStream_t stream) {
  const float* x      = (const float*)d_in[0];
  const float* mask   = (const float*)d_in[1];
  const float* qkv_w  = (const float*)d_in[2];
  const float* qkv_b  = (const float*)d_in[3];
  const float* proj_w = (const float*)d_in[4];
  const float* proj_b = (const float*)d_in[5];
  const float* rel    = (const float*)d_in[6];
  float* out = (float*)d_out;

  char* ws = (char*)d_ws;
  unsigned short* qkvb = (unsigned short*)(ws + OFF_QKV);
  unsigned short* xb   = (unsigned short*)(ws + OFF_XB);
  unsigned short* wqF  = (unsigned short*)(ws + OFF_WQF);
  unsigned short* wpF  = (unsigned short*)(ws + OFF_WPF);
  // bmt (16.78 MB) in d_out scratch: fully consumed by k_attn before final GEMM.
  float* bmt = (float*)d_out;

  k_cvt<<<2048, 256, 0, stream>>>(x, xb, M_ROWS * C_DIM / 4);
  k_transpose_cvt_frag<<<dim3(QKV_N / 32, C_DIM / 32), 256, 0, stream>>>(qkv_w, wqF, C_DIM, QKV_N);
  k_transpose_cvt_frag<<<dim3(C_DIM / 32, C_DIM / 32), 256, 0, stream>>>(proj_w, wpF, C_DIM, C_DIM);
  k_bm<<<(NMASK * NH * 64 * 64) / 256, 256, 0, stream>>>(mask, rel, bmt);

  // qkv = x @ qkv_w + qkv_b  (bf16 out), grid 784*12 = 9408 (%8==0)
  k_gemmh<1><<<(M_ROWS / 128) * (QKV_N / 128), 256, 0, stream>>>(
      xb, wqF, qkv_b, qkvb, M_ROWS, QKV_N);

  // attention -> attn_out (reuses xb region)
  k_attn<<<2048 * NH / 4, 256, 0, stream>>>(qkvb, bmt, xb);

  // out = attn_out @ proj_w + proj_b  (f32 out), grid 784*4 = 3136 (%8==0)
  k_gemmh<0><<<(M_ROWS / 128) * (C_DIM / 128), 256, 0, stream>>>(
      xb, wpF, proj_b, out, M_ROWS, C_DIM);
}

// Round 11
// 616.191 us; speedup vs baseline: 1.3550x; 1.3550x over previous
//
#include <hip/hip_runtime.h>
#include <hip/hip_bf16.h>
#include <stdint.h>

// Problem constants (match setup_inputs)
#define M_ROWS 100352   // 2048 * 49
#define C_DIM  512
#define QKV_N  1536
#define NH     16
#define HD     32
#define NWIN   49       // window tokens (7*7)
#define NMASK  64

typedef __attribute__((ext_vector_type(4))) float        f32x4;
typedef __attribute__((ext_vector_type(8))) short        bf16x8;
typedef __attribute__((ext_vector_type(4))) unsigned int u32x4;

static __device__ __forceinline__ unsigned short f32_to_bf16(float f) {
  union { float f; unsigned int u; } v; v.f = f;
  unsigned int u = v.u;
  return (unsigned short)((u + 0x7FFFu + ((u >> 16) & 1u)) >> 16);  // RNE
}

// global -> LDS direct DMA, 16B per lane. dest = wave-uniform base + lane*16.
static __device__ __forceinline__ void gload_lds16(const void* g, void* l) {
  __builtin_amdgcn_global_load_lds(
      (const __attribute__((address_space(1))) unsigned int*)g,
      (__attribute__((address_space(3))) unsigned int*)l, 16, 0, 0);
}

// ---------------------------------------------------------------- k_cvt
__global__ void k_cvt(const float* __restrict__ in, unsigned short* __restrict__ out, int n4) {
  int i = blockIdx.x * blockDim.x + threadIdx.x;
  int stride = gridDim.x * blockDim.x;
  for (; i < n4; i += stride) {
    float4 v = ((const float4*)in)[i];
    ushort4 o = make_ushort4(f32_to_bf16(v.x), f32_to_bf16(v.y),
                             f32_to_bf16(v.z), f32_to_bf16(v.w));
    ((ushort4*)out)[i] = o;
  }
}

// ------------------------------------------- transpose + convert weights
// in: K x N f32 (row-major), out: N x K bf16 (row-major) == B^T
__global__ void k_transpose_cvt(const float* __restrict__ in, unsigned short* __restrict__ out,
                                int K, int N) {
  __shared__ float t[32][33];
  const int n0 = blockIdx.x * 32, k0 = blockIdx.y * 32;
  const int tx = threadIdx.x & 31, ty = threadIdx.x >> 5;  // 32 x 8
#pragma unroll
  for (int rr = 0; rr < 32; rr += 8)
    t[ty + rr][tx] = in[(size_t)(k0 + ty + rr) * N + n0 + tx];
  __syncthreads();
#pragma unroll
  for (int rr = 0; rr < 32; rr += 8)
    out[(size_t)(n0 + ty + rr) * K + k0 + tx] = f32_to_bf16(t[tx][ty + rr]);
}

// ----------------------------------------- fused bias+mask table (padded)
__global__ __launch_bounds__(256) void k_bm(const float* __restrict__ mask,
                                            const float* __restrict__ rel,
                                            float* __restrict__ bmt) {
  const int idx = blockIdx.x * 256 + threadIdx.x;   // w<<16 | h<<12 | i<<6 | j
  const int j = idx & 63, i = (idx >> 6) & 63, h = (idx >> 12) & 15, w = idx >> 16;
  float v = -1e30f;
  if (i < NWIN && j < NWIN) {
    const int rpi = ((j / 7) - (i / 7) + 6) * 13;
    v = mask[w * (NWIN * NWIN) + i * NWIN + j] + rel[rpi * NH + h];
  }
  bmt[idx] = v;
}

#define WAITB(N)                                              \
  do {                                                        \
    asm volatile("s_waitcnt vmcnt(" #N ")" ::: "memory");     \
    __builtin_amdgcn_sched_barrier(0);                        \
    __builtin_amdgcn_s_barrier();                             \
    __builtin_amdgcn_sched_barrier(0);                        \
  } while (0)

// --------------------------------------------------- GEMM A (r5 4-phase)
// EXACT r5 K-loop (best measured: QKV 228.8 us).  Only changes: swapped
// MFMA operand order (mfma(b,a)) + packed epilogue (r7-verified mapping:
// lane holds rows m=16mi+lr, cols n=16nj+4lg+{0..3}).
template <int OUT_BF16>
__global__ __launch_bounds__(512, 2) void k_gemmA(const unsigned short* __restrict__ A,
                                                  const unsigned short* __restrict__ BT,
                                                  const float* __restrict__ bias,
                                                  void* __restrict__ Cout,
                                                  int M, int N, int K) {
  __shared__ __align__(16) unsigned short lds[2][2][16384];  // [buf][A|B] 128 KB
  const int tid = threadIdx.x;
  const int lane = tid & 63, wave = tid >> 6;
  const int wr = wave >> 2, wc = wave & 3;      // 2 x 4 wave grid
  const int lr = lane & 15, lg = lane >> 4;

  const int nwg = gridDim.x, q8 = nwg >> 3;
  const int wg = (blockIdx.x & 7) * q8 + (blockIdx.x >> 3);
  const int gx = N >> 8;
  const int bx = wg % gx, by = wg / gx;
  const int m0 = by << 8, n0 = bx << 8;

  const int srow = lane & 15;
  const int scol = (lane >> 4) * 8;
  const int sRG = wave >> 1;
  const int scg = wave & 1;

  const f32x4 fz = {0.f, 0.f, 0.f, 0.f};
  f32x4 acc[8][4];
#pragma unroll
  for (int i = 0; i < 8; ++i)
#pragma unroll
    for (int j = 0; j < 4; ++j) acc[i][j] = fz;

  const int NT = K >> 6;

  auto stageU = [&](const unsigned short* G, int gbase, int op, int t, int u) {
    const int RG = 4 * u + sRG;  // row-group 0..15
    gload_lds16(G + (size_t)(gbase + RG * 16 + srow) * K + (t << 6) + scg * 32 + scol,
                &lds[t & 1][op][(RG >> 3) * 8192 + (((RG & 7) << 1) + scg) * 512]);
  };

  const int roff = lg * 128 + lr * 8;

  bf16x8 af[4][2];
  bf16x8 bf[2][2];
  bf16x8 bg[2][2];

#define LDA(h, mh)                                                              \
  do {                                                                          \
    const unsigned short* la = &lds[(h) & 1][0][wr * 8192];                     \
    _Pragma("unroll") for (int m = 0; m < 4; ++m)                               \
    _Pragma("unroll") for (int ks = 0; ks < 2; ++ks)                            \
        af[m][ks] = *(const bf16x8*)(la + ((((mh)*4 + m) * 2 + ks) * 512) + roff); \
  } while (0)

#define LDB(h, nh, DST)                                                         \
  do {                                                                          \
    const unsigned short* lb = &lds[(h) & 1][1][(wc >> 1) * 8192];              \
    _Pragma("unroll") for (int n = 0; n < 2; ++n)                               \
    _Pragma("unroll") for (int ks = 0; ks < 2; ++ks)                            \
        DST[n][ks] = *(const bf16x8*)(lb + ((((wc & 1) * 4 + (nh)*2 + n) * 2 + ks) * 512) + roff); \
  } while (0)

#define MFMA16(mh, nh, B)                                                       \
  do {                                                                          \
    __builtin_amdgcn_s_setprio(1);                                              \
    _Pragma("unroll") for (int m = 0; m < 4; ++m)                               \
    _Pragma("unroll") for (int n = 0; n < 2; ++n)                               \
    _Pragma("unroll") for (int ks = 0; ks < 2; ++ks)                            \
        acc[(mh)*4 + m][(nh)*2 + n] = __builtin_amdgcn_mfma_f32_16x16x32_bf16(  \
            B[n][ks], af[m][ks], acc[(mh)*4 + m][(nh)*2 + n], 0, 0, 0);         \
    __builtin_amdgcn_s_setprio(0);                                              \
  } while (0)

  stageU(BT, n0, 1, 0, 0); stageU(BT, n0, 1, 0, 1);
  stageU(BT, n0, 1, 0, 2); stageU(BT, n0, 1, 0, 3);
  stageU(A,  m0, 0, 0, 0); stageU(A,  m0, 0, 0, 2);
  stageU(A,  m0, 0, 0, 1); stageU(A,  m0, 0, 0, 3);

  for (int h = 0; h < NT - 1; ++h) {
    const int t1 = h + 1;
    WAITB(2);
    stageU(BT, n0, 1, t1, 0); stageU(BT, n0, 1, t1, 1);
    LDA(h, 0);
    LDB(h, 0, bf);
    MFMA16(0, 0, bf);
    stageU(BT, n0, 1, t1, 2); stageU(BT, n0, 1, t1, 3);
    LDB(h, 1, bg);
    MFMA16(0, 1, bg);
    WAITB(4);
    stageU(A, m0, 0, t1, 0); stageU(A, m0, 0, t1, 2);
    LDA(h, 1);
    MFMA16(1, 1, bg);
    stageU(A, m0, 0, t1, 1); stageU(A, m0, 0, t1, 3);
    LDB(h, 0, bf);
    MFMA16(1, 0, bf);
  }
  {
    const int h = NT - 1;
    WAITB(2);
    LDA(h, 0);
    LDB(h, 0, bf);
    MFMA16(0, 0, bf);
    LDB(h, 1, bg);
    MFMA16(0, 1, bg);
    WAITB(0);
    LDA(h, 1);
    MFMA16(1, 1, bg);
    LDB(h, 0, bf);
    MFMA16(1, 0, bf);
  }
#undef LDA
#undef LDB
#undef MFMA16

  // packed epilogue (swapped mapping): rows m = 16mi+lr, cols n = 16nj+4lg+{0..3}
  f32x4 b4[4];
#pragma unroll
  for (int nj = 0; nj < 4; ++nj)
    b4[nj] = *(const f32x4*)(bias + n0 + wc * 64 + nj * 16 + 4 * lg);
#pragma unroll
  for (int mi = 0; mi < 8; ++mi) {
    const size_t row = (size_t)(m0 + wr * 128 + mi * 16 + lr);
#pragma unroll
    for (int nj = 0; nj < 4; ++nj) {
      const int colbase = n0 + wc * 64 + nj * 16 + 4 * lg;
      const float v0 = acc[mi][nj][0] + b4[nj][0];
      const float v1 = acc[mi][nj][1] + b4[nj][1];
      const float v2 = acc[mi][nj][2] + b4[nj][2];
      const float v3 = acc[mi][nj][3] + b4[nj][3];
      if (OUT_BF16) {
        uint2 st;
        st.x = (unsigned int)f32_to_bf16(v0) | ((unsigned int)f32_to_bf16(v1) << 16);
        st.y = (unsigned int)f32_to_bf16(v2) | ((unsigned int)f32_to_bf16(v3) << 16);
        *(uint2*)((unsigned short*)Cout + row * N + colbase) = st;
      } else {
        f32x4 st = {v0, v1, v2, v3};
        *(f32x4*)((float*)Cout + row * N + colbase) = st;
      }
    }
  }
}

// --------------------------------------------- GEMM B (2 blocks/CU probe)
// BM=256, BN=128, BK=32, 512 thr = 8 waves (4M x 2N), wave tile 64x64
// (acc 64 VGPR -> fits 128-reg budget at 4 waves/SIMD = 2 blocks/CU).
// LDS: A 16KB + B 8KB per buf, dbuf = 48KB -> occupancy-limited by VGPR to
// 2 blocks/CU (vs r5's 1): cross-block overlap absorbs barrier drains
// (m97/m114 mechanism).  Proven conflict-free subtile layout ([cg4][r16][8c]).
// 2-phase counted vmcnt: 3 loads/lane/tile; after issuing stage(t+1),
// outstanding = 6 -> vmcnt(3) drains tile t only.  Swapped packed epilogue.
template <int OUT_BF16>
__global__ __launch_bounds__(512, 4) void k_gemmB(const unsigned short* __restrict__ A,
                                                  const unsigned short* __restrict__ BT,
                                                  const float* __restrict__ bias,
                                                  void* __restrict__ Cout,
                                                  int M, int N) {
  __shared__ __align__(16) unsigned short ldsA[2][8192];  // 16 subtiles
  __shared__ __align__(16) unsigned short ldsB[2][4096];  // 8 subtiles
  const int tid = threadIdx.x;
  const int lane = tid & 63, wave = tid >> 6;
  const int wr = wave >> 1, wc = wave & 1;     // 4M x 2N
  const int lr = lane & 15, lg = lane >> 4;

  const int nwg = gridDim.x, q8 = nwg >> 3;
  const int wg = (blockIdx.x & 7) * q8 + (blockIdx.x >> 3);
  const int gx = N >> 7;
  const int bx = wg % gx, by = wg / gx;
  const int m0 = by << 8, n0 = bx << 7;

  const int srow = lane & 15;
  const int scol = (lane >> 4) * 8;

  const f32x4 fz = {0.f, 0.f, 0.f, 0.f};
  f32x4 acc[4][4];
#pragma unroll
  for (int i = 0; i < 4; ++i)
#pragma unroll
    for (int j = 0; j < 4; ++j) acc[i][j] = fz;

  // stage tile t (BK=32): A 2 loads + B 1 load per lane
  auto stage = [&](int t, int buf) {
    const int k0 = t << 5;
#pragma unroll
    for (int i = 0; i < 2; ++i) {
      const int s = wave * 2 + i;  // A subtile 0..15
      gload_lds16(A + (size_t)(m0 + s * 16 + srow) * C_DIM + k0 + scol,
                  &ldsA[buf][s * 512]);
    }
    gload_lds16(BT + (size_t)(n0 + wave * 16 + srow) * C_DIM + k0 + scol,
                &ldsB[buf][wave * 512]);
  };

  const int roff = lg * 128 + lr * 8;

  stage(0, 0);
  for (int t = 0; t < 16; ++t) {
    const int cur = t & 1;
    if (t < 15) {
      stage(t + 1, cur ^ 1);
      WAITB(3);                      // drain tile t's 3; keep t+1's 3 in flight
    } else {
      WAITB(0);
    }
    bf16x8 a_[4], b_[4];
#pragma unroll
    for (int mi = 0; mi < 4; ++mi)
      a_[mi] = *(const bf16x8*)(ldsA[cur] + (wr * 4 + mi) * 512 + roff);
#pragma unroll
    for (int nj = 0; nj < 4; ++nj)
      b_[nj] = *(const bf16x8*)(ldsB[cur] + (wc * 4 + nj) * 512 + roff);
    __builtin_amdgcn_s_setprio(1);
#pragma unroll
    for (int mi = 0; mi < 4; ++mi)
#pragma unroll
      for (int nj = 0; nj < 4; ++nj)
        acc[mi][nj] = __builtin_amdgcn_mfma_f32_16x16x32_bf16(b_[nj], a_[mi], acc[mi][nj], 0, 0, 0);
    __builtin_amdgcn_s_setprio(0);
    __builtin_amdgcn_s_barrier();    // readers done before stage(t+2) overwrites
    __builtin_amdgcn_sched_barrier(0);
  }

  f32x4 b4[4];
#pragma unroll
  for (int nj = 0; nj < 4; ++nj)
    b4[nj] = *(const f32x4*)(bias + n0 + wc * 64 + nj * 16 + 4 * lg);
#pragma unroll
  for (int mi = 0; mi < 4; ++mi) {
    const size_t row = (size_t)(m0 + wr * 64 + mi * 16 + lr);
#pragma unroll
    for (int nj = 0; nj < 4; ++nj) {
      const int colbase = n0 + wc * 64 + nj * 16 + 4 * lg;
      const float v0 = acc[mi][nj][0] + b4[nj][0];
      const float v1 = acc[mi][nj][1] + b4[nj][1];
      const float v2 = acc[mi][nj][2] + b4[nj][2];
      const float v3 = acc[mi][nj][3] + b4[nj][3];
      if (OUT_BF16) {
        uint2 st;
        st.x = (unsigned int)f32_to_bf16(v0) | ((unsigned int)f32_to_bf16(v1) << 16);
        st.y = (unsigned int)f32_to_bf16(v2) | ((unsigned int)f32_to_bf16(v3) << 16);
        *(uint2*)((unsigned short*)Cout + row * N + colbase) = st;
      } else {
        f32x4 st = {v0, v1, v2, v3};
        *(f32x4*)((float*)Cout + row * N + colbase) = st;
      }
    }
  }
}

// ------------------------------------------------------------- attention
// (r5-proven, unchanged)
__global__ __launch_bounds__(256) void k_attn(const unsigned short* __restrict__ qkv,
                                              const float* __restrict__ bmt,
                                              unsigned short* __restrict__ aout) {
  const int wave = threadIdx.x >> 6, lane = threadIdx.x & 63;
  const int lr = lane & 15, lg = lane >> 4;
  const int idx = blockIdx.x * 4 + wave;
  const int b = idx >> 4, h = idx & 15, w = b & 63;

  __shared__ __align__(16) unsigned short Pl[4][2048];
  __shared__ __align__(16) unsigned short Vt[4][2112];
  unsigned short* pl = Pl[wave];
  unsigned short* vt = Vt[wave];

  const unsigned short* qp = qkv + (size_t)b * NWIN * QKV_N + h * HD;
  const unsigned short* kp = qp + C_DIM;
  const unsigned short* vp = qp + 2 * C_DIM;

  bf16x8 kf[4], qf[4];
#pragma unroll
  for (int t = 0; t < 4; ++t) {
    kf[t] = *(const bf16x8*)(kp + (size_t)(t * 16 + lr) * QKV_N + lg * 8);
    qf[t] = *(const bf16x8*)(qp + (size_t)(t * 16 + lr) * QKV_N + lg * 8);
  }

  const u32x4 zv = {0u, 0u, 0u, 0u};
#pragma unroll
  for (int c0 = 0; c0 < 4; ++c0) {
    const int c = c0 * 64 + lane;
    const int key = c >> 2, d0 = (c & 3) << 3;
    union { u32x4 v; unsigned short s[8]; } tmp;
    tmp.v = (key < NWIN) ? *(const u32x4*)(vp + (size_t)key * QKV_N + d0) : zv;
#pragma unroll
    for (int jj = 0; jj < 8; ++jj) vt[(d0 + jj) * 66 + key] = tmp.s[jj];
  }

  const f32x4 fz = {0.f, 0.f, 0.f, 0.f};
  f32x4 s[4][4];
#pragma unroll
  for (int mi = 0; mi < 4; ++mi)
#pragma unroll
    for (int ni = 0; ni < 4; ++ni) s[mi][ni] = fz;
#pragma unroll
  for (int mi = 0; mi < 4; ++mi)
#pragma unroll
    for (int ni = 0; ni < 4; ++ni)
      s[mi][ni] = __builtin_amdgcn_mfma_f32_16x16x32_bf16(kf[mi], qf[ni], s[mi][ni], 0, 0, 0);

  union VU { unsigned int u[4]; bf16x8 v; };
  VU vfr[2][2];
#pragma unroll
  for (int nj = 0; nj < 2; ++nj)
#pragma unroll
    for (int ks = 0; ks < 2; ++ks) {
      const int base = ((16 * nj + lr) * 66 + 32 * ks + 8 * lg) >> 1;
#pragma unroll
      for (int u = 0; u < 4; ++u) vfr[nj][ks].u[u] = ((const unsigned int*)vt)[base + u];
    }

  const float scale = 0.1767766952966369f;
  const float* tbl = bmt + ((size_t)(w * NH + h) << 12);

  f32x4 o[4][2];
#pragma unroll
  for (int qi = 0; qi < 4; ++qi)
#pragma unroll
    for (int nj = 0; nj < 2; ++nj) o[qi][nj] = fz;

#pragma unroll
  for (int ni = 0; ni < 4; ++ni) {
    float v[16];
    float mx = -3e38f;
#pragma unroll
    for (int mi = 0; mi < 4; ++mi) {
      const f32x4 t4 = *(const f32x4*)(tbl + (16 * ni + lr) * 64 + 16 * mi + 4 * lg);
#pragma unroll
      for (int r = 0; r < 4; ++r) {
        v[mi * 4 + r] = fmaf(s[mi][ni][r], scale, t4[r]);
        mx = fmaxf(mx, v[mi * 4 + r]);
      }
    }
    mx = fmaxf(mx, __shfl_xor(mx, 16));
    mx = fmaxf(mx, __shfl_xor(mx, 32));
    float sum = 0.f;
#pragma unroll
    for (int t = 0; t < 16; ++t) {
      v[t] = __expf(v[t] - mx);
      sum += v[t];
    }
    sum += __shfl_xor(sum, 16);
    sum += __shfl_xor(sum, 32);
    const float inv = __builtin_amdgcn_rcpf(sum);

    const int ip = 16 * (ni & 1) + lr;
#pragma unroll
    for (int mi = 0; mi < 4; ++mi) {
      const unsigned int lo = (unsigned int)f32_to_bf16(v[mi * 4 + 0] * inv) |
                              ((unsigned int)f32_to_bf16(v[mi * 4 + 1] * inv) << 16);
      const unsigned int hi = (unsigned int)f32_to_bf16(v[mi * 4 + 2] * inv) |
                              ((unsigned int)f32_to_bf16(v[mi * 4 + 3] * inv) << 16);
      const int byteoff = 32 * mi + 8 * lg;
      const int sw = byteoff ^ ((ip & 7) << 4);
      uint2 w2; w2.x = lo; w2.y = hi;
      *(uint2*)((char*)pl + ip * 128 + sw) = w2;
    }

    if (ni & 1) {
      asm volatile("s_waitcnt lgkmcnt(0)" ::: "memory");
      __builtin_amdgcn_sched_barrier(0);
      const int half = ni >> 1;
#pragma unroll
      for (int q2 = 0; q2 < 2; ++q2) {
        const int qi = half * 2 + q2;
        const int ipr = 16 * q2 + lr;
#pragma unroll
        for (int ks = 0; ks < 2; ++ks) {
          const int bo = 64 * ks + 16 * lg;
          const int swr = bo ^ ((ipr & 7) << 4);
          const bf16x8 pa = *(const bf16x8*)((const char*)pl + ipr * 128 + swr);
#pragma unroll
          for (int nj = 0; nj < 2; ++nj)
            o[qi][nj] = __builtin_amdgcn_mfma_f32_16x16x32_bf16(pa, vfr[nj][ks].v, o[qi][nj], 0, 0, 0);
        }
      }
    }
  }

  const size_t orow = (size_t)b * NWIN;
#pragma unroll
  for (int qi = 0; qi < 4; ++qi)
#pragma unroll
    for (int r = 0; r < 4; ++r) {
      const int i = 16 * qi + 4 * lg + r;
      if (i < NWIN) {
#pragma unroll
        for (int nj = 0; nj < 2; ++nj)
          aout[(orow + i) * C_DIM + h * HD + 16 * nj + lr] = f32_to_bf16(o[qi][nj][r]);
      }
    }
}

// ---------------------------------------------------------------- launch
static const size_t SZ_QKV = (size_t)M_ROWS * QKV_N * 2;
static const size_t SZ_XB  = (size_t)M_ROWS * C_DIM * 2;
static const size_t SZ_WQ  = (size_t)QKV_N * C_DIM * 2;
static const size_t OFF_QKV = 0;
static const size_t OFF_XB  = OFF_QKV + SZ_QKV;   // x_bf16, later attn_out
static const size_t OFF_WQ  = OFF_XB + SZ_XB;
static const size_t OFF_WP  = OFF_WQ + SZ_WQ;

extern "C" void kernel_launch(void* const* d_in, const int* in_sizes, int n_in,
                              void* d_out, int out_size, void* d_ws, size_t ws_size,
                              hipStream_t stream) {
  const float* x      = (const float*)d_in[0];
  const float* mask   = (const float*)d_in[1];
  const float* qkv_w  = (const float*)d_in[2];
  const float* qkv_b  = (const float*)d_in[3];
  const float* proj_w = (const float*)d_in[4];
  const float* proj_b = (const float*)d_in[5];
  const float* rel    = (const float*)d_in[6];
  float* out = (float*)d_out;

  char* ws = (char*)d_ws;
  unsigned short* qkvb = (unsigned short*)(ws + OFF_QKV);
  unsigned short* xb   = (unsigned short*)(ws + OFF_XB);
  unsigned short* wqT  = (unsigned short*)(ws + OFF_WQ);
  unsigned short* wpT  = (unsigned short*)(ws + OFF_WP);
  // bmt (16.78 MB) in d_out scratch: fully consumed by k_attn before final GEMM.
  float* bmt = (float*)d_out;

  k_cvt<<<2048, 256, 0, stream>>>(x, xb, M_ROWS * C_DIM / 4);
  k_transpose_cvt<<<dim3(QKV_N / 32, C_DIM / 32), 256, 0, stream>>>(qkv_w, wqT, C_DIM, QKV_N);
  k_transpose_cvt<<<dim3(C_DIM / 32, C_DIM / 32), 256, 0, stream>>>(proj_w, wpT, C_DIM, C_DIM);
  k_bm<<<(NMASK * NH * 64 * 64) / 256, 256, 0, stream>>>(mask, rel, bmt);

  // qkv = x @ qkv_w + qkv_b  (bf16 out), grid 6*392 = 2352 (%8==0)
  k_gemmA<1><<<(QKV_N / 256) * (M_ROWS / 256), 512, 0, stream>>>(
      xb, wqT, qkv_b, qkvb, M_ROWS, QKV_N, C_DIM);

  // attention -> attn_out (reuses xb region)
  k_attn<<<2048 * NH / 4, 256, 0, stream>>>(qkvb, bmt, xb);

  // out = attn_out @ proj_w + proj_b  (f32 out), grid 392*4 = 1568 (%8==0)
  k_gemmB<0><<<(M_ROWS / 256) * (C_DIM / 128), 512, 0, stream>>>(
      xb, wpT, proj_b, out, M_ROWS, C_DIM);
}

// Round 12
// 539.446 us; speedup vs baseline: 1.5478x; 1.1423x over previous
//
#include <hip/hip_runtime.h>
#include <hip/hip_bf16.h>
#include <stdint.h>

// Problem constants (match setup_inputs)
#define M_ROWS 100352   // 2048 * 49
#define C_DIM  512
#define QKV_N  1536
#define NH     16
#define HD     32
#define NWIN   49       // window tokens (7*7)
#define NMASK  64

typedef __attribute__((ext_vector_type(4))) float        f32x4;
typedef __attribute__((ext_vector_type(8))) short        bf16x8;
typedef __attribute__((ext_vector_type(4))) unsigned int u32x4;

static __device__ __forceinline__ unsigned short f32_to_bf16(float f) {
  union { float f; unsigned int u; } v; v.f = f;
  unsigned int u = v.u;
  return (unsigned short)((u + 0x7FFFu + ((u >> 16) & 1u)) >> 16);  // RNE
}

// global -> LDS direct DMA, 16B per lane. dest = wave-uniform base + lane*16.
static __device__ __forceinline__ void gload_lds16(const void* g, void* l) {
  __builtin_amdgcn_global_load_lds(
      (const __attribute__((address_space(1))) unsigned int*)g,
      (__attribute__((address_space(3))) unsigned int*)l, 16, 0, 0);
}

// ---------------------------------------------------------------- k_cvt
__global__ void k_cvt(const float* __restrict__ in, unsigned short* __restrict__ out, int n4) {
  int i = blockIdx.x * blockDim.x + threadIdx.x;
  int stride = gridDim.x * blockDim.x;
  for (; i < n4; i += stride) {
    float4 v = ((const float4*)in)[i];
    ushort4 o = make_ushort4(f32_to_bf16(v.x), f32_to_bf16(v.y),
                             f32_to_bf16(v.z), f32_to_bf16(v.w));
    ((ushort4*)out)[i] = o;
  }
}

// ------------------------------------------- transpose + convert weights
// in: K x N f32 (row-major), out: N x K bf16 (row-major) == B^T
__global__ void k_transpose_cvt(const float* __restrict__ in, unsigned short* __restrict__ out,
                                int K, int N) {
  __shared__ float t[32][33];
  const int n0 = blockIdx.x * 32, k0 = blockIdx.y * 32;
  const int tx = threadIdx.x & 31, ty = threadIdx.x >> 5;  // 32 x 8
#pragma unroll
  for (int rr = 0; rr < 32; rr += 8)
    t[ty + rr][tx] = in[(size_t)(k0 + ty + rr) * N + n0 + tx];
  __syncthreads();
#pragma unroll
  for (int rr = 0; rr < 32; rr += 8)
    out[(size_t)(n0 + ty + rr) * K + k0 + tx] = f32_to_bf16(t[tx][ty + rr]);
}

// ----------------------------------------- fused bias+mask table (padded)
__global__ __launch_bounds__(256) void k_bm(const float* __restrict__ mask,
                                            const float* __restrict__ rel,
                                            float* __restrict__ bmt) {
  const int idx = blockIdx.x * 256 + threadIdx.x;   // w<<16 | h<<12 | i<<6 | j
  const int j = idx & 63, i = (idx >> 6) & 63, h = (idx >> 12) & 15, w = idx >> 16;
  float v = -1e30f;
  if (i < NWIN && j < NWIN) {
    const int rpi = ((j / 7) - (i / 7) + 6) * 13;
    v = mask[w * (NWIN * NWIN) + i * NWIN + j] + rel[rpi * NH + h];
  }
  bmt[idx] = v;
}

#define WAITB(N)                                              \
  do {                                                        \
    asm volatile("s_waitcnt vmcnt(" #N ")" ::: "memory");     \
    __builtin_amdgcn_sched_barrier(0);                        \
    __builtin_amdgcn_s_barrier();                             \
    __builtin_amdgcn_sched_barrier(0);                        \
  } while (0)

// ------------------------------------------------------------------ GEMM
// EXACT r5 4-phase 256x256 body (best measured config: QKV 228.8 us).
// Wrapped in two distinctly-NAMED kernels so rocprof separates them.
template <int OUT_BF16>
static __device__ __forceinline__ void gemm256_body(const unsigned short* __restrict__ A,
                                                    const unsigned short* __restrict__ BT,
                                                    const float* __restrict__ bias,
                                                    void* __restrict__ Cout,
                                                    int M, int N, int K,
                                                    unsigned short* lds0) {
  unsigned short (*lds)[2][16384] = (unsigned short (*)[2][16384])lds0;
  const int tid = threadIdx.x;
  const int lane = tid & 63, wave = tid >> 6;
  const int wr = wave >> 2, wc = wave & 3;      // 2 x 4 wave grid
  const int lr = lane & 15, lg = lane >> 4;

  // bijective XCD swizzle (gridDim.x % 8 == 0 for all call sites)
  const int nwg = gridDim.x, q8 = nwg >> 3;
  const int wg = (blockIdx.x & 7) * q8 + (blockIdx.x >> 3);
  const int gx = N >> 8;
  const int bx = wg % gx, by = wg / gx;
  const int m0 = by << 8, n0 = bx << 8;

  const int srow = lane & 15;
  const int scol = (lane >> 4) * 8;
  const int sRG = wave >> 1;
  const int scg = wave & 1;

  const f32x4 fz = {0.f, 0.f, 0.f, 0.f};
  f32x4 acc[8][4];
#pragma unroll
  for (int i = 0; i < 8; ++i)
#pragma unroll
    for (int j = 0; j < 4; ++j) acc[i][j] = fz;

  const int NT = K >> 6;

  auto stageU = [&](const unsigned short* G, int gbase, int op, int t, int u) {
    const int RG = 4 * u + sRG;  // row-group 0..15
    gload_lds16(G + (size_t)(gbase + RG * 16 + srow) * K + (t << 6) + scg * 32 + scol,
                &lds[t & 1][op][(RG >> 3) * 8192 + (((RG & 7) << 1) + scg) * 512]);
  };

  const int roff = lg * 128 + lr * 8;

  bf16x8 af[4][2];
  bf16x8 bf[2][2];
  bf16x8 bg[2][2];

#define LDA(h, mh)                                                              \
  do {                                                                          \
    const unsigned short* la = &lds[(h) & 1][0][wr * 8192];                     \
    _Pragma("unroll") for (int m = 0; m < 4; ++m)                               \
    _Pragma("unroll") for (int ks = 0; ks < 2; ++ks)                            \
        af[m][ks] = *(const bf16x8*)(la + ((((mh)*4 + m) * 2 + ks) * 512) + roff); \
  } while (0)

#define LDB(h, nh, DST)                                                         \
  do {                                                                          \
    const unsigned short* lb = &lds[(h) & 1][1][(wc >> 1) * 8192];              \
    _Pragma("unroll") for (int n = 0; n < 2; ++n)                               \
    _Pragma("unroll") for (int ks = 0; ks < 2; ++ks)                            \
        DST[n][ks] = *(const bf16x8*)(lb + ((((wc & 1) * 4 + (nh)*2 + n) * 2 + ks) * 512) + roff); \
  } while (0)

#define MFMA16(mh, nh, B)                                                       \
  do {                                                                          \
    __builtin_amdgcn_s_setprio(1);                                              \
    _Pragma("unroll") for (int m = 0; m < 4; ++m)                               \
    _Pragma("unroll") for (int n = 0; n < 2; ++n)                               \
    _Pragma("unroll") for (int ks = 0; ks < 2; ++ks)                            \
        acc[(mh)*4 + m][(nh)*2 + n] = __builtin_amdgcn_mfma_f32_16x16x32_bf16(  \
            af[m][ks], B[n][ks], acc[(mh)*4 + m][(nh)*2 + n], 0, 0, 0);         \
    __builtin_amdgcn_s_setprio(0);                                              \
  } while (0)

  // prologue: tile 0, unit order B0 B1 B2 B3 A0 A2 A1 A3 (8 loads/lane)
  stageU(BT, n0, 1, 0, 0); stageU(BT, n0, 1, 0, 1);
  stageU(BT, n0, 1, 0, 2); stageU(BT, n0, 1, 0, 3);
  stageU(A,  m0, 0, 0, 0); stageU(A,  m0, 0, 0, 2);
  stageU(A,  m0, 0, 0, 1); stageU(A,  m0, 0, 0, 3);

  for (int h = 0; h < NT - 1; ++h) {
    const int t1 = h + 1;
    WAITB(2);
    stageU(BT, n0, 1, t1, 0); stageU(BT, n0, 1, t1, 1);
    LDA(h, 0);
    LDB(h, 0, bf);
    MFMA16(0, 0, bf);
    stageU(BT, n0, 1, t1, 2); stageU(BT, n0, 1, t1, 3);
    LDB(h, 1, bg);
    MFMA16(0, 1, bg);
    WAITB(4);
    stageU(A, m0, 0, t1, 0); stageU(A, m0, 0, t1, 2);
    LDA(h, 1);
    MFMA16(1, 1, bg);
    stageU(A, m0, 0, t1, 1); stageU(A, m0, 0, t1, 3);
    LDB(h, 0, bf);
    MFMA16(1, 0, bf);
  }
  {  // last tile, peeled
    const int h = NT - 1;
    WAITB(2);
    LDA(h, 0);
    LDB(h, 0, bf);
    MFMA16(0, 0, bf);
    LDB(h, 1, bg);
    MFMA16(0, 1, bg);
    WAITB(0);
    LDA(h, 1);
    MFMA16(1, 1, bg);
    LDB(h, 0, bf);
    MFMA16(1, 0, bf);
  }
#undef LDA
#undef LDB
#undef MFMA16

  float bv[4];
#pragma unroll
  for (int nj = 0; nj < 4; ++nj) bv[nj] = bias[n0 + wc * 64 + nj * 16 + lr];
#pragma unroll
  for (int mi = 0; mi < 8; ++mi)
#pragma unroll
    for (int nj = 0; nj < 4; ++nj)
#pragma unroll
      for (int r = 0; r < 4; ++r) {
        const int row = m0 + wr * 128 + mi * 16 + 4 * lg + r;
        const int col = n0 + wc * 64 + nj * 16 + lr;
        const float v = acc[mi][nj][r] + bv[nj];
        if (OUT_BF16)
          ((unsigned short*)Cout)[(size_t)row * N + col] = f32_to_bf16(v);
        else
          ((float*)Cout)[(size_t)row * N + col] = v;
      }
}

__global__ __launch_bounds__(512, 2) void k_gemm_qkv(const unsigned short* __restrict__ A,
                                                     const unsigned short* __restrict__ BT,
                                                     const float* __restrict__ bias,
                                                     void* __restrict__ Cout,
                                                     int M, int N, int K) {
  __shared__ __align__(16) unsigned short lds[2][2][16384];  // 128 KB
  gemm256_body<1>(A, BT, bias, Cout, M, N, K, &lds[0][0][0]);
}

__global__ __launch_bounds__(512, 2) void k_gemm_proj(const unsigned short* __restrict__ A,
                                                      const unsigned short* __restrict__ BT,
                                                      const float* __restrict__ bias,
                                                      void* __restrict__ Cout,
                                                      int M, int N, int K) {
  __shared__ __align__(16) unsigned short lds[2][2][16384];  // 128 KB
  gemm256_body<0>(A, BT, bias, Cout, M, N, K, &lds[0][0][0]);
}

// ------------------------------------------------------------- attention
// (r5-proven, unchanged)
__global__ __launch_bounds__(256) void k_attn(const unsigned short* __restrict__ qkv,
                                              const float* __restrict__ bmt,
                                              unsigned short* __restrict__ aout) {
  const int wave = threadIdx.x >> 6, lane = threadIdx.x & 63;
  const int lr = lane & 15, lg = lane >> 4;
  const int idx = blockIdx.x * 4 + wave;
  const int b = idx >> 4, h = idx & 15, w = b & 63;

  __shared__ __align__(16) unsigned short Pl[4][2048];
  __shared__ __align__(16) unsigned short Vt[4][2112];
  unsigned short* pl = Pl[wave];
  unsigned short* vt = Vt[wave];

  const unsigned short* qp = qkv + (size_t)b * NWIN * QKV_N + h * HD;
  const unsigned short* kp = qp + C_DIM;
  const unsigned short* vp = qp + 2 * C_DIM;

  bf16x8 kf[4], qf[4];
#pragma unroll
  for (int t = 0; t < 4; ++t) {
    kf[t] = *(const bf16x8*)(kp + (size_t)(t * 16 + lr) * QKV_N + lg * 8);
    qf[t] = *(const bf16x8*)(qp + (size_t)(t * 16 + lr) * QKV_N + lg * 8);
  }

  const u32x4 zv = {0u, 0u, 0u, 0u};
#pragma unroll
  for (int c0 = 0; c0 < 4; ++c0) {
    const int c = c0 * 64 + lane;
    const int key = c >> 2, d0 = (c & 3) << 3;
    union { u32x4 v; unsigned short s[8]; } tmp;
    tmp.v = (key < NWIN) ? *(const u32x4*)(vp + (size_t)key * QKV_N + d0) : zv;
#pragma unroll
    for (int jj = 0; jj < 8; ++jj) vt[(d0 + jj) * 66 + key] = tmp.s[jj];
  }

  const f32x4 fz = {0.f, 0.f, 0.f, 0.f};
  f32x4 s[4][4];
#pragma unroll
  for (int mi = 0; mi < 4; ++mi)
#pragma unroll
    for (int ni = 0; ni < 4; ++ni) s[mi][ni] = fz;
#pragma unroll
  for (int mi = 0; mi < 4; ++mi)
#pragma unroll
    for (int ni = 0; ni < 4; ++ni)
      s[mi][ni] = __builtin_amdgcn_mfma_f32_16x16x32_bf16(kf[mi], qf[ni], s[mi][ni], 0, 0, 0);

  union VU { unsigned int u[4]; bf16x8 v; };
  VU vfr[2][2];
#pragma unroll
  for (int nj = 0; nj < 2; ++nj)
#pragma unroll
    for (int ks = 0; ks < 2; ++ks) {
      const int base = ((16 * nj + lr) * 66 + 32 * ks + 8 * lg) >> 1;
#pragma unroll
      for (int u = 0; u < 4; ++u) vfr[nj][ks].u[u] = ((const unsigned int*)vt)[base + u];
    }

  const float scale = 0.1767766952966369f;
  const float* tbl = bmt + ((size_t)(w * NH + h) << 12);

  f32x4 o[4][2];
#pragma unroll
  for (int qi = 0; qi < 4; ++qi)
#pragma unroll
    for (int nj = 0; nj < 2; ++nj) o[qi][nj] = fz;

#pragma unroll
  for (int ni = 0; ni < 4; ++ni) {
    float v[16];
    float mx = -3e38f;
#pragma unroll
    for (int mi = 0; mi < 4; ++mi) {
      const f32x4 t4 = *(const f32x4*)(tbl + (16 * ni + lr) * 64 + 16 * mi + 4 * lg);
#pragma unroll
      for (int r = 0; r < 4; ++r) {
        v[mi * 4 + r] = fmaf(s[mi][ni][r], scale, t4[r]);
        mx = fmaxf(mx, v[mi * 4 + r]);
      }
    }
    mx = fmaxf(mx, __shfl_xor(mx, 16));
    mx = fmaxf(mx, __shfl_xor(mx, 32));
    float sum = 0.f;
#pragma unroll
    for (int t = 0; t < 16; ++t) {
      v[t] = __expf(v[t] - mx);
      sum += v[t];
    }
    sum += __shfl_xor(sum, 16);
    sum += __shfl_xor(sum, 32);
    const float inv = __builtin_amdgcn_rcpf(sum);

    const int ip = 16 * (ni & 1) + lr;
#pragma unroll
    for (int mi = 0; mi < 4; ++mi) {
      const unsigned int lo = (unsigned int)f32_to_bf16(v[mi * 4 + 0] * inv) |
                              ((unsigned int)f32_to_bf16(v[mi * 4 + 1] * inv) << 16);
      const unsigned int hi = (unsigned int)f32_to_bf16(v[mi * 4 + 2] * inv) |
                              ((unsigned int)f32_to_bf16(v[mi * 4 + 3] * inv) << 16);
      const int byteoff = 32 * mi + 8 * lg;
      const int sw = byteoff ^ ((ip & 7) << 4);
      uint2 w2; w2.x = lo; w2.y = hi;
      *(uint2*)((char*)pl + ip * 128 + sw) = w2;
    }

    if (ni & 1) {
      asm volatile("s_waitcnt lgkmcnt(0)" ::: "memory");
      __builtin_amdgcn_sched_barrier(0);
      const int half = ni >> 1;
#pragma unroll
      for (int q2 = 0; q2 < 2; ++q2) {
        const int qi = half * 2 + q2;
        const int ipr = 16 * q2 + lr;
#pragma unroll
        for (int ks = 0; ks < 2; ++ks) {
          const int bo = 64 * ks + 16 * lg;
          const int swr = bo ^ ((ipr & 7) << 4);
          const bf16x8 pa = *(const bf16x8*)((const char*)pl + ipr * 128 + swr);
#pragma unroll
          for (int nj = 0; nj < 2; ++nj)
            o[qi][nj] = __builtin_amdgcn_mfma_f32_16x16x32_bf16(pa, vfr[nj][ks].v, o[qi][nj], 0, 0, 0);
        }
      }
    }
  }

  const size_t orow = (size_t)b * NWIN;
#pragma unroll
  for (int qi = 0; qi < 4; ++qi)
#pragma unroll
    for (int r = 0; r < 4; ++r) {
      const int i = 16 * qi + 4 * lg + r;
      if (i < NWIN) {
#pragma unroll
        for (int nj = 0; nj < 2; ++nj)
          aout[(orow + i) * C_DIM + h * HD + 16 * nj + lr] = f32_to_bf16(o[qi][nj][r]);
      }
    }
}

// ---------------------------------------------------------------- launch
static const size_t SZ_QKV = (size_t)M_ROWS * QKV_N * 2;
static const size_t SZ_XB  = (size_t)M_ROWS * C_DIM * 2;
static const size_t SZ_WQ  = (size_t)QKV_N * C_DIM * 2;
static const size_t OFF_QKV = 0;
static const size_t OFF_XB  = OFF_QKV + SZ_QKV;   // x_bf16, later attn_out
static const size_t OFF_WQ  = OFF_XB + SZ_XB;
static const size_t OFF_WP  = OFF_WQ + SZ_WQ;

extern "C" void kernel_launch(void* const* d_in, const int* in_sizes, int n_in,
                              void* d_out, int out_size, void* d_ws, size_t ws_size,
                              hipStream_t stream) {
  const float* x      = (const float*)d_in[0];
  const float* mask   = (const float*)d_in[1];
  const float* qkv_w  = (const float*)d_in[2];
  const float* qkv_b  = (const float*)d_in[3];
  const float* proj_w = (const float*)d_in[4];
  const float* proj_b = (const float*)d_in[5];
  const float* rel    = (const float*)d_in[6];
  float* out = (float*)d_out;

  char* ws = (char*)d_ws;
  unsigned short* qkvb = (unsigned short*)(ws + OFF_QKV);
  unsigned short* xb   = (unsigned short*)(ws + OFF_XB);
  unsigned short* wqT  = (unsigned short*)(ws + OFF_WQ);
  unsigned short* wpT  = (unsigned short*)(ws + OFF_WP);
  // bmt (16.78 MB) in d_out scratch: fully consumed by k_attn before final GEMM.
  float* bmt = (float*)d_out;

  k_cvt<<<2048, 256, 0, stream>>>(x, xb, M_ROWS * C_DIM / 4);
  k_transpose_cvt<<<dim3(QKV_N / 32, C_DIM / 32), 256, 0, stream>>>(qkv_w, wqT, C_DIM, QKV_N);
  k_transpose_cvt<<<dim3(C_DIM / 32, C_DIM / 32), 256, 0, stream>>>(proj_w, wpT, C_DIM, C_DIM);
  k_bm<<<(NMASK * NH * 64 * 64) / 256, 256, 0, stream>>>(mask, rel, bmt);

  // qkv = x @ qkv_w + qkv_b  (bf16 out), grid 6*392 = 2352 (%8==0)
  k_gemm_qkv<<<(QKV_N / 256) * (M_ROWS / 256), 512, 0, stream>>>(
      xb, wqT, qkv_b, qkvb, M_ROWS, QKV_N, C_DIM);

  // attention -> attn_out (reuses xb region)
  k_attn<<<2048 * NH / 4, 256, 0, stream>>>(qkvb, bmt, xb);

  // out = attn_out @ proj_w + proj_b  (f32 out), grid 2*392 = 784 (%8==0)
  k_gemm_proj<<<(C_DIM / 256) * (M_ROWS / 256), 512, 0, stream>>>(
      xb, wpT, proj_b, out, M_ROWS, C_DIM, C_DIM);
}

// Round 13
// 518.567 us; speedup vs baseline: 1.6101x; 1.0403x over previous
//
#include <hip/hip_runtime.h>
#include <hip/hip_bf16.h>
#include <stdint.h>

// Problem constants (match setup_inputs)
#define M_ROWS 100352   // 2048 * 49
#define C_DIM  512
#define QKV_N  1536
#define NH     16
#define HD     32
#define NWIN   49       // window tokens (7*7)
#define NMASK  64

typedef __attribute__((ext_vector_type(4))) float        f32x4;
typedef __attribute__((ext_vector_type(8))) short        bf16x8;
typedef __attribute__((ext_vector_type(4))) unsigned int u32x4;

static __device__ __forceinline__ unsigned short f32_to_bf16(float f) {
  union { float f; unsigned int u; } v; v.f = f;
  unsigned int u = v.u;
  return (unsigned short)((u + 0x7FFFu + ((u >> 16) & 1u)) >> 16);  // RNE
}

// global -> LDS direct DMA, 16B per lane. dest = wave-uniform base + lane*16.
static __device__ __forceinline__ void gload_lds16(const void* g, void* l) {
  __builtin_amdgcn_global_load_lds(
      (const __attribute__((address_space(1))) unsigned int*)g,
      (__attribute__((address_space(3))) unsigned int*)l, 16, 0, 0);
}

// ---------------------------------------------------------------- k_cvt
__global__ void k_cvt(const float* __restrict__ in, unsigned short* __restrict__ out, int n4) {
  int i = blockIdx.x * blockDim.x + threadIdx.x;
  int stride = gridDim.x * blockDim.x;
  for (; i < n4; i += stride) {
    float4 v = ((const float4*)in)[i];
    ushort4 o = make_ushort4(f32_to_bf16(v.x), f32_to_bf16(v.y),
                             f32_to_bf16(v.z), f32_to_bf16(v.w));
    ((ushort4*)out)[i] = o;
  }
}

// ------------------------------------------- transpose + convert weights
// in: K x N f32 (row-major), out: N x K bf16 (row-major) == B^T
__global__ void k_transpose_cvt(const float* __restrict__ in, unsigned short* __restrict__ out,
                                int K, int N) {
  __shared__ float t[32][33];
  const int n0 = blockIdx.x * 32, k0 = blockIdx.y * 32;
  const int tx = threadIdx.x & 31, ty = threadIdx.x >> 5;  // 32 x 8
#pragma unroll
  for (int rr = 0; rr < 32; rr += 8)
    t[ty + rr][tx] = in[(size_t)(k0 + ty + rr) * N + n0 + tx];
  __syncthreads();
#pragma unroll
  for (int rr = 0; rr < 32; rr += 8)
    out[(size_t)(n0 + ty + rr) * K + k0 + tx] = f32_to_bf16(t[tx][ty + rr]);
}

// ----------------------------------------- fused bias+mask table (padded)
__global__ __launch_bounds__(256) void k_bm(const float* __restrict__ mask,
                                            const float* __restrict__ rel,
                                            float* __restrict__ bmt) {
  const int idx = blockIdx.x * 256 + threadIdx.x;   // w<<16 | h<<12 | i<<6 | j
  const int j = idx & 63, i = (idx >> 6) & 63, h = (idx >> 12) & 15, w = idx >> 16;
  float v = -1e30f;
  if (i < NWIN && j < NWIN) {
    const int rpi = ((j / 7) - (i / 7) + 6) * 13;
    v = mask[w * (NWIN * NWIN) + i * NWIN + j] + rel[rpi * NH + h];
  }
  bmt[idx] = v;
}

#define WAITB(N)                                              \
  do {                                                        \
    asm volatile("s_waitcnt vmcnt(" #N ")" ::: "memory");     \
    __builtin_amdgcn_sched_barrier(0);                        \
    __builtin_amdgcn_s_barrier();                             \
    __builtin_amdgcn_sched_barrier(0);                        \
  } while (0)

// ------------------------------------------------------------------ GEMM
// EXACT r5/r12 4-phase 256x256 K-loop (best measured: QKV 226.5 us, total
// 539.4 reproduced to 0.01%).  K-loop is schedule-fragile (r11: in-loop
// operand swap cost +40us) -> NEVER touched.  Epilogues differ by OUT_MODE:
//   0 = f32 row-major + bias
//   1 = bf16 row-major + bias
//   2 = bf16 qkv-blocked [b][h][which][49][32] + bias  (attn-friendly:
//       q/k frag loads and V staging in k_attn become contiguous-block reads
//       instead of 3072B-stride gathers)
template <int OUT_MODE>
static __device__ __forceinline__ void gemm256_body(const unsigned short* __restrict__ A,
                                                    const unsigned short* __restrict__ BT,
                                                    const float* __restrict__ bias,
                                                    void* __restrict__ Cout,
                                                    int M, int N, int K,
                                                    unsigned short* lds0) {
  unsigned short (*lds)[2][16384] = (unsigned short (*)[2][16384])lds0;
  const int tid = threadIdx.x;
  const int lane = tid & 63, wave = tid >> 6;
  const int wr = wave >> 2, wc = wave & 3;      // 2 x 4 wave grid
  const int lr = lane & 15, lg = lane >> 4;

  // bijective XCD swizzle (gridDim.x % 8 == 0 for all call sites)
  const int nwg = gridDim.x, q8 = nwg >> 3;
  const int wg = (blockIdx.x & 7) * q8 + (blockIdx.x >> 3);
  const int gx = N >> 8;
  const int bx = wg % gx, by = wg / gx;
  const int m0 = by << 8, n0 = bx << 8;

  const int srow = lane & 15;
  const int scol = (lane >> 4) * 8;
  const int sRG = wave >> 1;
  const int scg = wave & 1;

  const f32x4 fz = {0.f, 0.f, 0.f, 0.f};
  f32x4 acc[8][4];
#pragma unroll
  for (int i = 0; i < 8; ++i)
#pragma unroll
    for (int j = 0; j < 4; ++j) acc[i][j] = fz;

  const int NT = K >> 6;

  auto stageU = [&](const unsigned short* G, int gbase, int op, int t, int u) {
    const int RG = 4 * u + sRG;  // row-group 0..15
    gload_lds16(G + (size_t)(gbase + RG * 16 + srow) * K + (t << 6) + scg * 32 + scol,
                &lds[t & 1][op][(RG >> 3) * 8192 + (((RG & 7) << 1) + scg) * 512]);
  };

  const int roff = lg * 128 + lr * 8;

  bf16x8 af[4][2];
  bf16x8 bf[2][2];
  bf16x8 bg[2][2];

#define LDA(h, mh)                                                              \
  do {                                                                          \
    const unsigned short* la = &lds[(h) & 1][0][wr * 8192];                     \
    _Pragma("unroll") for (int m = 0; m < 4; ++m)                               \
    _Pragma("unroll") for (int ks = 0; ks < 2; ++ks)                            \
        af[m][ks] = *(const bf16x8*)(la + ((((mh)*4 + m) * 2 + ks) * 512) + roff); \
  } while (0)

#define LDB(h, nh, DST)                                                         \
  do {                                                                          \
    const unsigned short* lb = &lds[(h) & 1][1][(wc >> 1) * 8192];              \
    _Pragma("unroll") for (int n = 0; n < 2; ++n)                               \
    _Pragma("unroll") for (int ks = 0; ks < 2; ++ks)                            \
        DST[n][ks] = *(const bf16x8*)(lb + ((((wc & 1) * 4 + (nh)*2 + n) * 2 + ks) * 512) + roff); \
  } while (0)

#define MFMA16(mh, nh, B)                                                       \
  do {                                                                          \
    __builtin_amdgcn_s_setprio(1);                                              \
    _Pragma("unroll") for (int m = 0; m < 4; ++m)                               \
    _Pragma("unroll") for (int n = 0; n < 2; ++n)                               \
    _Pragma("unroll") for (int ks = 0; ks < 2; ++ks)                            \
        acc[(mh)*4 + m][(nh)*2 + n] = __builtin_amdgcn_mfma_f32_16x16x32_bf16(  \
            af[m][ks], B[n][ks], acc[(mh)*4 + m][(nh)*2 + n], 0, 0, 0);         \
    __builtin_amdgcn_s_setprio(0);                                              \
  } while (0)

  // prologue: tile 0, unit order B0 B1 B2 B3 A0 A2 A1 A3 (8 loads/lane)
  stageU(BT, n0, 1, 0, 0); stageU(BT, n0, 1, 0, 1);
  stageU(BT, n0, 1, 0, 2); stageU(BT, n0, 1, 0, 3);
  stageU(A,  m0, 0, 0, 0); stageU(A,  m0, 0, 0, 2);
  stageU(A,  m0, 0, 0, 1); stageU(A,  m0, 0, 0, 3);

  for (int h = 0; h < NT - 1; ++h) {
    const int t1 = h + 1;
    WAITB(2);
    stageU(BT, n0, 1, t1, 0); stageU(BT, n0, 1, t1, 1);
    LDA(h, 0);
    LDB(h, 0, bf);
    MFMA16(0, 0, bf);
    stageU(BT, n0, 1, t1, 2); stageU(BT, n0, 1, t1, 3);
    LDB(h, 1, bg);
    MFMA16(0, 1, bg);
    WAITB(4);
    stageU(A, m0, 0, t1, 0); stageU(A, m0, 0, t1, 2);
    LDA(h, 1);
    MFMA16(1, 1, bg);
    stageU(A, m0, 0, t1, 1); stageU(A, m0, 0, t1, 3);
    LDB(h, 0, bf);
    MFMA16(1, 0, bf);
  }
  {  // last tile, peeled
    const int h = NT - 1;
    WAITB(2);
    LDA(h, 0);
    LDB(h, 0, bf);
    MFMA16(0, 0, bf);
    LDB(h, 1, bg);
    MFMA16(0, 1, bg);
    WAITB(0);
    LDA(h, 1);
    MFMA16(1, 1, bg);
    LDB(h, 0, bf);
    MFMA16(1, 0, bf);
  }
#undef LDA
#undef LDB
#undef MFMA16

  float bv[4];
#pragma unroll
  for (int nj = 0; nj < 4; ++nj) bv[nj] = bias[n0 + wc * 64 + nj * 16 + lr];
#pragma unroll
  for (int mi = 0; mi < 8; ++mi)
#pragma unroll
    for (int nj = 0; nj < 4; ++nj)
#pragma unroll
      for (int r = 0; r < 4; ++r) {
        const int row = m0 + wr * 128 + mi * 16 + 4 * lg + r;
        const int col = n0 + wc * 64 + nj * 16 + lr;
        const float v = acc[mi][nj][r] + bv[nj];
        if (OUT_MODE == 2) {
          // qkv-blocked: row -> (b = row/49, i = row%49); col -> (which, h, d)
          const unsigned int b = (unsigned int)row / 49u;
          const unsigned int i = (unsigned int)row - b * 49u;
          const int which = col >> 9, hh = (col >> 5) & 15, d = col & 31;
          ((unsigned short*)Cout)[(((size_t)b * NH + hh) * 147 + which * 49 + i) * 32 + d] =
              f32_to_bf16(v);
        } else if (OUT_MODE == 1) {
          ((unsigned short*)Cout)[(size_t)row * N + col] = f32_to_bf16(v);
        } else {
          ((float*)Cout)[(size_t)row * N + col] = v;
        }
      }
}

__global__ __launch_bounds__(512, 2) void k_gemm_qkv(const unsigned short* __restrict__ A,
                                                     const unsigned short* __restrict__ BT,
                                                     const float* __restrict__ bias,
                                                     void* __restrict__ Cout,
                                                     int M, int N, int K) {
  __shared__ __align__(16) unsigned short lds[2][2][16384];  // 128 KB
  gemm256_body<2>(A, BT, bias, Cout, M, N, K, &lds[0][0][0]);
}

__global__ __launch_bounds__(512, 2) void k_gemm_proj(const unsigned short* __restrict__ A,
                                                      const unsigned short* __restrict__ BT,
                                                      const float* __restrict__ bias,
                                                      void* __restrict__ Cout,
                                                      int M, int N, int K) {
  __shared__ __align__(16) unsigned short lds[2][2][16384];  // 128 KB
  gemm256_body<0>(A, BT, bias, Cout, M, N, K, &lds[0][0][0]);
}

// ------------------------------------------------------------- attention
// 4 waves/block, one (b,h) per wave, zero barriers.  qkv in blocked layout
// [b][h][{q,k,v}][49][32]: q/k frag loads hit a contiguous 3.1KB block
// (16 cache lines per b128 instead of 64 at the old 3072B row stride);
// V staging is a fully-coalesced 1KB/instruction read.  Frag rows 49..63
// spill into the adjacent k/v block of the SAME (b,h) - finite bf16,
// masked by the -1e30 bmt padding (same guarantee as before).
__global__ __launch_bounds__(256) void k_attn(const unsigned short* __restrict__ qkv,
                                              const float* __restrict__ bmt,
                                              unsigned short* __restrict__ aout) {
  const int wave = threadIdx.x >> 6, lane = threadIdx.x & 63;
  const int lr = lane & 15, lg = lane >> 4;
  const int idx = blockIdx.x * 4 + wave;
  const int b = idx >> 4, h = idx & 15, w = b & 63;

  __shared__ __align__(16) unsigned short Pl[4][2048];
  __shared__ __align__(16) unsigned short Vt[4][2112];
  unsigned short* pl = Pl[wave];
  unsigned short* vt = Vt[wave];

  const unsigned short* qp = qkv + ((size_t)(b * NH + h) * 147) * 32;
  const unsigned short* kp = qp + 49 * 32;
  const unsigned short* vp = qp + 2 * 49 * 32;

  bf16x8 kf[4], qf[4];
#pragma unroll
  for (int t = 0; t < 4; ++t) {
    kf[t] = *(const bf16x8*)(kp + (t * 16 + lr) * 32 + lg * 8);
    qf[t] = *(const bf16x8*)(qp + (t * 16 + lr) * 32 + lg * 8);
  }

  const u32x4 zv = {0u, 0u, 0u, 0u};
#pragma unroll
  for (int c0 = 0; c0 < 4; ++c0) {
    const int c = c0 * 64 + lane;
    const int key = c >> 2, d0 = (c & 3) << 3;
    union { u32x4 v; unsigned short s[8]; } tmp;
    tmp.v = (key < NWIN) ? *(const u32x4*)(vp + key * 32 + d0) : zv;
#pragma unroll
    for (int jj = 0; jj < 8; ++jj) vt[(d0 + jj) * 66 + key] = tmp.s[jj];
  }

  const f32x4 fz = {0.f, 0.f, 0.f, 0.f};
  f32x4 s[4][4];
#pragma unroll
  for (int mi = 0; mi < 4; ++mi)
#pragma unroll
    for (int ni = 0; ni < 4; ++ni) s[mi][ni] = fz;
#pragma unroll
  for (int mi = 0; mi < 4; ++mi)
#pragma unroll
    for (int ni = 0; ni < 4; ++ni)
      s[mi][ni] = __builtin_amdgcn_mfma_f32_16x16x32_bf16(kf[mi], qf[ni], s[mi][ni], 0, 0, 0);

  union VU { unsigned int u[4]; bf16x8 v; };
  VU vfr[2][2];
#pragma unroll
  for (int nj = 0; nj < 2; ++nj)
#pragma unroll
    for (int ks = 0; ks < 2; ++ks) {
      const int base = ((16 * nj + lr) * 66 + 32 * ks + 8 * lg) >> 1;
#pragma unroll
      for (int u = 0; u < 4; ++u) vfr[nj][ks].u[u] = ((const unsigned int*)vt)[base + u];
    }

  const float scale = 0.1767766952966369f;
  const float* tbl = bmt + ((size_t)(w * NH + h) << 12);

  f32x4 o[4][2];
#pragma unroll
  for (int qi = 0; qi < 4; ++qi)
#pragma unroll
    for (int nj = 0; nj < 2; ++nj) o[qi][nj] = fz;

#pragma unroll
  for (int ni = 0; ni < 4; ++ni) {
    float v[16];
    float mx = -3e38f;
#pragma unroll
    for (int mi = 0; mi < 4; ++mi) {
      const f32x4 t4 = *(const f32x4*)(tbl + (16 * ni + lr) * 64 + 16 * mi + 4 * lg);
#pragma unroll
      for (int r = 0; r < 4; ++r) {
        v[mi * 4 + r] = fmaf(s[mi][ni][r], scale, t4[r]);
        mx = fmaxf(mx, v[mi * 4 + r]);
      }
    }
    mx = fmaxf(mx, __shfl_xor(mx, 16));
    mx = fmaxf(mx, __shfl_xor(mx, 32));
    float sum = 0.f;
#pragma unroll
    for (int t = 0; t < 16; ++t) {
      v[t] = __expf(v[t] - mx);
      sum += v[t];
    }
    sum += __shfl_xor(sum, 16);
    sum += __shfl_xor(sum, 32);
    const float inv = __builtin_amdgcn_rcpf(sum);

    const int ip = 16 * (ni & 1) + lr;
#pragma unroll
    for (int mi = 0; mi < 4; ++mi) {
      const unsigned int lo = (unsigned int)f32_to_bf16(v[mi * 4 + 0] * inv) |
                              ((unsigned int)f32_to_bf16(v[mi * 4 + 1] * inv) << 16);
      const unsigned int hi = (unsigned int)f32_to_bf16(v[mi * 4 + 2] * inv) |
                              ((unsigned int)f32_to_bf16(v[mi * 4 + 3] * inv) << 16);
      const int byteoff = 32 * mi + 8 * lg;
      const int sw = byteoff ^ ((ip & 7) << 4);
      uint2 w2; w2.x = lo; w2.y = hi;
      *(uint2*)((char*)pl + ip * 128 + sw) = w2;
    }

    if (ni & 1) {
      asm volatile("s_waitcnt lgkmcnt(0)" ::: "memory");
      __builtin_amdgcn_sched_barrier(0);
      const int half = ni >> 1;
#pragma unroll
      for (int q2 = 0; q2 < 2; ++q2) {
        const int qi = half * 2 + q2;
        const int ipr = 16 * q2 + lr;
#pragma unroll
        for (int ks = 0; ks < 2; ++ks) {
          const int bo = 64 * ks + 16 * lg;
          const int swr = bo ^ ((ipr & 7) << 4);
          const bf16x8 pa = *(const bf16x8*)((const char*)pl + ipr * 128 + swr);
#pragma unroll
          for (int nj = 0; nj < 2; ++nj)
            o[qi][nj] = __builtin_amdgcn_mfma_f32_16x16x32_bf16(pa, vfr[nj][ks].v, o[qi][nj], 0, 0, 0);
        }
      }
    }
  }

  const size_t orow = (size_t)b * NWIN;
#pragma unroll
  for (int qi = 0; qi < 4; ++qi)
#pragma unroll
    for (int r = 0; r < 4; ++r) {
      const int i = 16 * qi + 4 * lg + r;
      if (i < NWIN) {
#pragma unroll
        for (int nj = 0; nj < 2; ++nj)
          aout[(orow + i) * C_DIM + h * HD + 16 * nj + lr] = f32_to_bf16(o[qi][nj][r]);
      }
    }
}

// ---------------------------------------------------------------- launch
static const size_t SZ_QKV = (size_t)M_ROWS * QKV_N * 2;   // 308 MB (blocked layout, same size)
static const size_t SZ_XB  = (size_t)M_ROWS * C_DIM * 2;
static const size_t SZ_WQ  = (size_t)QKV_N * C_DIM * 2;
static const size_t OFF_QKV = 0;
static const size_t OFF_XB  = OFF_QKV + SZ_QKV;   // x_bf16, later attn_out
static const size_t OFF_WQ  = OFF_XB + SZ_XB;
static const size_t OFF_WP  = OFF_WQ + SZ_WQ;

extern "C" void kernel_launch(void* const* d_in, const int* in_sizes, int n_in,
                              void* d_out, int out_size, void* d_ws, size_t ws_size,
                              hipStream_t stream) {
  const float* x      = (const float*)d_in[0];
  const float* mask   = (const float*)d_in[1];
  const float* qkv_w  = (const float*)d_in[2];
  const float* qkv_b  = (const float*)d_in[3];
  const float* proj_w = (const float*)d_in[4];
  const float* proj_b = (const float*)d_in[5];
  const float* rel    = (const float*)d_in[6];
  float* out = (float*)d_out;

  char* ws = (char*)d_ws;
  unsigned short* qkvb = (unsigned short*)(ws + OFF_QKV);
  unsigned short* xb   = (unsigned short*)(ws + OFF_XB);
  unsigned short* wqT  = (unsigned short*)(ws + OFF_WQ);
  unsigned short* wpT  = (unsigned short*)(ws + OFF_WP);
  // bmt (16.78 MB) in d_out scratch: fully consumed by k_attn before final GEMM.
  float* bmt = (float*)d_out;

  k_cvt<<<2048, 256, 0, stream>>>(x, xb, M_ROWS * C_DIM / 4);
  k_transpose_cvt<<<dim3(QKV_N / 32, C_DIM / 32), 256, 0, stream>>>(qkv_w, wqT, C_DIM, QKV_N);
  k_transpose_cvt<<<dim3(C_DIM / 32, C_DIM / 32), 256, 0, stream>>>(proj_w, wpT, C_DIM, C_DIM);
  k_bm<<<(NMASK * NH * 64 * 64) / 256, 256, 0, stream>>>(mask, rel, bmt);

  // qkv = x @ qkv_w + qkv_b  (bf16, blocked layout), grid 6*392 = 2352 (%8==0)
  k_gemm_qkv<<<(QKV_N / 256) * (M_ROWS / 256), 512, 0, stream>>>(
      xb, wqT, qkv_b, qkvb, M_ROWS, QKV_N, C_DIM);

  // attention -> attn_out (reuses xb region)
  k_attn<<<2048 * NH / 4, 256, 0, stream>>>(qkvb, bmt, xb);

  // out = attn_out @ proj_w + proj_b  (f32 out), grid 2*392 = 784 (%8==0)
  k_gemm_proj<<<(C_DIM / 256) * (M_ROWS / 256), 512, 0, stream>>>(
      xb, wpT, proj_b, out, M_ROWS, C_DIM, C_DIM);
}

// Round 14
// 492.308 us; speedup vs baseline: 1.6960x; 1.0533x over previous
//
#include <hip/hip_runtime.h>
#include <hip/hip_bf16.h>
#include <stdint.h>

// Problem constants (match setup_inputs)
#define M_ROWS 100352   // 2048 * 49
#define C_DIM  512
#define QKV_N  1536
#define NH     16
#define HD     32
#define NWIN   49       // window tokens (7*7)
#define NMASK  64

typedef __attribute__((ext_vector_type(4))) float        f32x4;
typedef __attribute__((ext_vector_type(8))) short        bf16x8;
typedef __attribute__((ext_vector_type(4))) unsigned int u32x4;

static __device__ __forceinline__ unsigned short f32_to_bf16(float f) {
  union { float f; unsigned int u; } v; v.f = f;
  unsigned int u = v.u;
  return (unsigned short)((u + 0x7FFFu + ((u >> 16) & 1u)) >> 16);  // RNE
}

// global -> LDS direct DMA, 16B per lane. dest = wave-uniform base + lane*16.
static __device__ __forceinline__ void gload_lds16(const void* g, void* l) {
  __builtin_amdgcn_global_load_lds(
      (const __attribute__((address_space(1))) unsigned int*)g,
      (__attribute__((address_space(3))) unsigned int*)l, 16, 0, 0);
}

// ---------------------------------------------------------------- k_cvt
__global__ void k_cvt(const float* __restrict__ in, unsigned short* __restrict__ out, int n4) {
  int i = blockIdx.x * blockDim.x + threadIdx.x;
  int stride = gridDim.x * blockDim.x;
  for (; i < n4; i += stride) {
    float4 v = ((const float4*)in)[i];
    ushort4 o = make_ushort4(f32_to_bf16(v.x), f32_to_bf16(v.y),
                             f32_to_bf16(v.z), f32_to_bf16(v.w));
    ((ushort4*)out)[i] = o;
  }
}

// ------------------------------------------- transpose + convert weights
// in: K x N f32 (row-major), out: N x K bf16 (row-major) == B^T
__global__ void k_transpose_cvt(const float* __restrict__ in, unsigned short* __restrict__ out,
                                int K, int N) {
  __shared__ float t[32][33];
  const int n0 = blockIdx.x * 32, k0 = blockIdx.y * 32;
  const int tx = threadIdx.x & 31, ty = threadIdx.x >> 5;  // 32 x 8
#pragma unroll
  for (int rr = 0; rr < 32; rr += 8)
    t[ty + rr][tx] = in[(size_t)(k0 + ty + rr) * N + n0 + tx];
  __syncthreads();
#pragma unroll
  for (int rr = 0; rr < 32; rr += 8)
    out[(size_t)(n0 + ty + rr) * K + k0 + tx] = f32_to_bf16(t[tx][ty + rr]);
}

// ----------------------------------------- fused bias+mask table (padded)
__global__ __launch_bounds__(256) void k_bm(const float* __restrict__ mask,
                                            const float* __restrict__ rel,
                                            float* __restrict__ bmt) {
  const int idx = blockIdx.x * 256 + threadIdx.x;   // w<<16 | h<<12 | i<<6 | j
  const int j = idx & 63, i = (idx >> 6) & 63, h = (idx >> 12) & 15, w = idx >> 16;
  float v = -1e30f;
  if (i < NWIN && j < NWIN) {
    const int rpi = ((j / 7) - (i / 7) + 6) * 13;
    v = mask[w * (NWIN * NWIN) + i * NWIN + j] + rel[rpi * NH + h];
  }
  bmt[idx] = v;
}

#define WAITB(N)                                              \
  do {                                                        \
    asm volatile("s_waitcnt vmcnt(" #N ")" ::: "memory");     \
    __builtin_amdgcn_sched_barrier(0);                        \
    __builtin_amdgcn_s_barrier();                             \
    __builtin_amdgcn_sched_barrier(0);                        \
  } while (0)

// ------------------------------------------------------------------ GEMM
// EXACT r5/r12 4-phase 256x256 K-loop (schedule-fragile; never touched).
// OUT_MODE: 0 = f32 row-major, 1 = bf16 row-major,
//           2 = bf16 qkv-blocked [b][h][{q,k,v}][49][32] (attn-friendly).
template <int OUT_MODE>
static __device__ __forceinline__ void gemm256_body(const unsigned short* __restrict__ A,
                                                    const unsigned short* __restrict__ BT,
                                                    const float* __restrict__ bias,
                                                    void* __restrict__ Cout,
                                                    int M, int N, int K,
                                                    unsigned short* lds0) {
  unsigned short (*lds)[2][16384] = (unsigned short (*)[2][16384])lds0;
  const int tid = threadIdx.x;
  const int lane = tid & 63, wave = tid >> 6;
  const int wr = wave >> 2, wc = wave & 3;      // 2 x 4 wave grid
  const int lr = lane & 15, lg = lane >> 4;

  // bijective XCD swizzle (gridDim.x % 8 == 0 for all call sites)
  const int nwg = gridDim.x, q8 = nwg >> 3;
  const int wg = (blockIdx.x & 7) * q8 + (blockIdx.x >> 3);
  const int gx = N >> 8;
  const int bx = wg % gx, by = wg / gx;
  const int m0 = by << 8, n0 = bx << 8;

  const int srow = lane & 15;
  const int scol = (lane >> 4) * 8;
  const int sRG = wave >> 1;
  const int scg = wave & 1;

  const f32x4 fz = {0.f, 0.f, 0.f, 0.f};
  f32x4 acc[8][4];
#pragma unroll
  for (int i = 0; i < 8; ++i)
#pragma unroll
    for (int j = 0; j < 4; ++j) acc[i][j] = fz;

  const int NT = K >> 6;

  auto stageU = [&](const unsigned short* G, int gbase, int op, int t, int u) {
    const int RG = 4 * u + sRG;  // row-group 0..15
    gload_lds16(G + (size_t)(gbase + RG * 16 + srow) * K + (t << 6) + scg * 32 + scol,
                &lds[t & 1][op][(RG >> 3) * 8192 + (((RG & 7) << 1) + scg) * 512]);
  };

  const int roff = lg * 128 + lr * 8;

  bf16x8 af[4][2];
  bf16x8 bf[2][2];
  bf16x8 bg[2][2];

#define LDA(h, mh)                                                              \
  do {                                                                          \
    const unsigned short* la = &lds[(h) & 1][0][wr * 8192];                     \
    _Pragma("unroll") for (int m = 0; m < 4; ++m)                               \
    _Pragma("unroll") for (int ks = 0; ks < 2; ++ks)                            \
        af[m][ks] = *(const bf16x8*)(la + ((((mh)*4 + m) * 2 + ks) * 512) + roff); \
  } while (0)

#define LDB(h, nh, DST)                                                         \
  do {                                                                          \
    const unsigned short* lb = &lds[(h) & 1][1][(wc >> 1) * 8192];              \
    _Pragma("unroll") for (int n = 0; n < 2; ++n)                               \
    _Pragma("unroll") for (int ks = 0; ks < 2; ++ks)                            \
        DST[n][ks] = *(const bf16x8*)(lb + ((((wc & 1) * 4 + (nh)*2 + n) * 2 + ks) * 512) + roff); \
  } while (0)

#define MFMA16(mh, nh, B)                                                       \
  do {                                                                          \
    __builtin_amdgcn_s_setprio(1);                                              \
    _Pragma("unroll") for (int m = 0; m < 4; ++m)                               \
    _Pragma("unroll") for (int n = 0; n < 2; ++n)                               \
    _Pragma("unroll") for (int ks = 0; ks < 2; ++ks)                            \
        acc[(mh)*4 + m][(nh)*2 + n] = __builtin_amdgcn_mfma_f32_16x16x32_bf16(  \
            af[m][ks], B[n][ks], acc[(mh)*4 + m][(nh)*2 + n], 0, 0, 0);         \
    __builtin_amdgcn_s_setprio(0);                                              \
  } while (0)

  // prologue: tile 0, unit order B0 B1 B2 B3 A0 A2 A1 A3 (8 loads/lane)
  stageU(BT, n0, 1, 0, 0); stageU(BT, n0, 1, 0, 1);
  stageU(BT, n0, 1, 0, 2); stageU(BT, n0, 1, 0, 3);
  stageU(A,  m0, 0, 0, 0); stageU(A,  m0, 0, 0, 2);
  stageU(A,  m0, 0, 0, 1); stageU(A,  m0, 0, 0, 3);

  for (int h = 0; h < NT - 1; ++h) {
    const int t1 = h + 1;
    WAITB(2);
    stageU(BT, n0, 1, t1, 0); stageU(BT, n0, 1, t1, 1);
    LDA(h, 0);
    LDB(h, 0, bf);
    MFMA16(0, 0, bf);
    stageU(BT, n0, 1, t1, 2); stageU(BT, n0, 1, t1, 3);
    LDB(h, 1, bg);
    MFMA16(0, 1, bg);
    WAITB(4);
    stageU(A, m0, 0, t1, 0); stageU(A, m0, 0, t1, 2);
    LDA(h, 1);
    MFMA16(1, 1, bg);
    stageU(A, m0, 0, t1, 1); stageU(A, m0, 0, t1, 3);
    LDB(h, 0, bf);
    MFMA16(1, 0, bf);
  }
  {  // last tile, peeled
    const int h = NT - 1;
    WAITB(2);
    LDA(h, 0);
    LDB(h, 0, bf);
    MFMA16(0, 0, bf);
    LDB(h, 1, bg);
    MFMA16(0, 1, bg);
    WAITB(0);
    LDA(h, 1);
    MFMA16(1, 1, bg);
    LDB(h, 0, bf);
    MFMA16(1, 0, bf);
  }
#undef LDA
#undef LDB
#undef MFMA16

  float bv[4];
#pragma unroll
  for (int nj = 0; nj < 4; ++nj) bv[nj] = bias[n0 + wc * 64 + nj * 16 + lr];
#pragma unroll
  for (int mi = 0; mi < 8; ++mi)
#pragma unroll
    for (int nj = 0; nj < 4; ++nj)
#pragma unroll
      for (int r = 0; r < 4; ++r) {
        const int row = m0 + wr * 128 + mi * 16 + 4 * lg + r;
        const int col = n0 + wc * 64 + nj * 16 + lr;
        const float v = acc[mi][nj][r] + bv[nj];
        if (OUT_MODE == 2) {
          // qkv-blocked: row -> (b = row/49, i = row%49); col -> (which, h, d)
          const unsigned int b = (unsigned int)row / 49u;
          const unsigned int i = (unsigned int)row - b * 49u;
          const int which = col >> 9, hh = (col >> 5) & 15, d = col & 31;
          ((unsigned short*)Cout)[(((size_t)b * NH + hh) * 147 + which * 49 + i) * 32 + d] =
              f32_to_bf16(v);
        } else if (OUT_MODE == 1) {
          ((unsigned short*)Cout)[(size_t)row * N + col] = f32_to_bf16(v);
        } else {
          ((float*)Cout)[(size_t)row * N + col] = v;
        }
      }
}

__global__ __launch_bounds__(512, 2) void k_gemm_qkv(const unsigned short* __restrict__ A,
                                                     const unsigned short* __restrict__ BT,
                                                     const float* __restrict__ bias,
                                                     void* __restrict__ Cout,
                                                     int M, int N, int K) {
  __shared__ __align__(16) unsigned short lds[2][2][16384];  // 128 KB
  gemm256_body<2>(A, BT, bias, Cout, M, N, K, &lds[0][0][0]);
}

__global__ __launch_bounds__(512, 2) void k_gemm_proj(const unsigned short* __restrict__ A,
                                                      const unsigned short* __restrict__ BT,
                                                      const float* __restrict__ bias,
                                                      void* __restrict__ Cout,
                                                      int M, int N, int K) {
  __shared__ __align__(16) unsigned short lds[2][2][16384];  // 128 KB
  gemm256_body<0>(A, BT, bias, Cout, M, N, K, &lds[0][0][0]);
}

// ------------------------------------------------------------- attention
// Block = (w, h, tg): 4 waves handle b = w + 64*(4*tg + wave) — all share
// the SAME (w,h) bias+mask table, which is staged ONCE into LDS (16 KB,
// stride-66 f32 rows -> ~2-way read conflicts).  Cuts bmt global traffic
// 4x (512->128 MB), and the XCD swizzle clusters same-w blocks per XCD:
// XCD x sees w in [8x,8x+8) -> 8w x 16h x 16KB = 2 MB < 4 MB L2 -> table
// reads are L2-resident.  One __syncthreads (after QK^T, hiding staging
// latency under MFMA).  qkv in blocked layout [b][h][{q,k,v}][49][32] (r13).
__global__ __launch_bounds__(256) void k_attn(const unsigned short* __restrict__ qkv,
                                              const float* __restrict__ bmt,
                                              unsigned short* __restrict__ aout) {
  const int wave = threadIdx.x >> 6, lane = threadIdx.x & 63;
  const int lr = lane & 15, lg = lane >> 4;

  // bijective XCD swizzle over 8192 blocks (q8 = 1024): XCD x gets
  // s in [1024x, 1024x+1024) -> w in [8x, 8x+8).
  const int s = (blockIdx.x & 7) * 1024 + (blockIdx.x >> 3);
  const int w = s >> 7, h = (s >> 3) & 15, tg = s & 7;
  const int b = w + 64 * (tg * 4 + wave);

  __shared__ float bml[64 * 66];                        // 16.9 KB shared table
  __shared__ __align__(16) unsigned short Pl[4][2048];  // per-wave P
  __shared__ __align__(16) unsigned short Vt[4][2112];  // per-wave V^T
  unsigned short* pl = Pl[wave];
  unsigned short* vt = Vt[wave];

  // ---- stage bmt(w,h) -> LDS (coalesced 16 KB read; issued first) ----
  const float* tbl = bmt + ((size_t)(w * NH + h) << 12);
#pragma unroll
  for (int it = 0; it < 4; ++it) {
    const int c = threadIdx.x + 256 * it;   // 16B chunk 0..1023
    const int row = c >> 4, col4 = c & 15;
    const f32x4 t4 = *(const f32x4*)(tbl + row * 64 + col4 * 4);
    float* dst = &bml[row * 66 + col4 * 4];
    dst[0] = t4[0]; dst[1] = t4[1]; dst[2] = t4[2]; dst[3] = t4[3];
  }

  const unsigned short* qp = qkv + ((size_t)(b * NH + h) * 147) * 32;
  const unsigned short* kp = qp + 49 * 32;
  const unsigned short* vp = qp + 2 * 49 * 32;

  bf16x8 kf[4], qf[4];
#pragma unroll
  for (int t = 0; t < 4; ++t) {
    kf[t] = *(const bf16x8*)(kp + (t * 16 + lr) * 32 + lg * 8);
    qf[t] = *(const bf16x8*)(qp + (t * 16 + lr) * 32 + lg * 8);
  }

  const u32x4 zv = {0u, 0u, 0u, 0u};
#pragma unroll
  for (int c0 = 0; c0 < 4; ++c0) {
    const int c = c0 * 64 + lane;
    const int key = c >> 2, d0 = (c & 3) << 3;
    union { u32x4 v; unsigned short ss[8]; } tmp;
    tmp.v = (key < NWIN) ? *(const u32x4*)(vp + key * 32 + d0) : zv;
#pragma unroll
    for (int jj = 0; jj < 8; ++jj) vt[(d0 + jj) * 66 + key] = tmp.ss[jj];
  }

  const f32x4 fz = {0.f, 0.f, 0.f, 0.f};
  f32x4 s4[4][4];
#pragma unroll
  for (int mi = 0; mi < 4; ++mi)
#pragma unroll
    for (int ni = 0; ni < 4; ++ni) s4[mi][ni] = fz;
#pragma unroll
  for (int mi = 0; mi < 4; ++mi)
#pragma unroll
    for (int ni = 0; ni < 4; ++ni)
      s4[mi][ni] = __builtin_amdgcn_mfma_f32_16x16x32_bf16(kf[mi], qf[ni], s4[mi][ni], 0, 0, 0);

  union VU { unsigned int u[4]; bf16x8 v; };
  VU vfr[2][2];
#pragma unroll
  for (int nj = 0; nj < 2; ++nj)
#pragma unroll
    for (int ks = 0; ks < 2; ++ks) {
      const int base = ((16 * nj + lr) * 66 + 32 * ks + 8 * lg) >> 1;
#pragma unroll
      for (int u = 0; u < 4; ++u) vfr[nj][ks].u[u] = ((const unsigned int*)vt)[base + u];
    }

  __syncthreads();  // bml staged (QK^T hid the latency)

  const float scale = 0.1767766952966369f;

  f32x4 o[4][2];
#pragma unroll
  for (int qi = 0; qi < 4; ++qi)
#pragma unroll
    for (int nj = 0; nj < 2; ++nj) o[qi][nj] = fz;

#pragma unroll
  for (int ni = 0; ni < 4; ++ni) {
    float v[16];
    float mx = -3e38f;
    const float* brow = &bml[(16 * ni + lr) * 66];
#pragma unroll
    for (int mi = 0; mi < 4; ++mi) {
#pragma unroll
      for (int r = 0; r < 4; ++r) {
        v[mi * 4 + r] = fmaf(s4[mi][ni][r], scale, brow[16 * mi + 4 * lg + r]);
        mx = fmaxf(mx, v[mi * 4 + r]);
      }
    }
    mx = fmaxf(mx, __shfl_xor(mx, 16));
    mx = fmaxf(mx, __shfl_xor(mx, 32));
    float sum = 0.f;
#pragma unroll
    for (int t = 0; t < 16; ++t) {
      v[t] = __expf(v[t] - mx);
      sum += v[t];
    }
    sum += __shfl_xor(sum, 16);
    sum += __shfl_xor(sum, 32);
    const float inv = __builtin_amdgcn_rcpf(sum);

    const int ip = 16 * (ni & 1) + lr;
#pragma unroll
    for (int mi = 0; mi < 4; ++mi) {
      const unsigned int lo = (unsigned int)f32_to_bf16(v[mi * 4 + 0] * inv) |
                              ((unsigned int)f32_to_bf16(v[mi * 4 + 1] * inv) << 16);
      const unsigned int hi = (unsigned int)f32_to_bf16(v[mi * 4 + 2] * inv) |
                              ((unsigned int)f32_to_bf16(v[mi * 4 + 3] * inv) << 16);
      const int byteoff = 32 * mi + 8 * lg;
      const int sw = byteoff ^ ((ip & 7) << 4);
      uint2 w2; w2.x = lo; w2.y = hi;
      *(uint2*)((char*)pl + ip * 128 + sw) = w2;
    }

    if (ni & 1) {
      asm volatile("s_waitcnt lgkmcnt(0)" ::: "memory");
      __builtin_amdgcn_sched_barrier(0);
      const int half = ni >> 1;
#pragma unroll
      for (int q2 = 0; q2 < 2; ++q2) {
        const int qi = half * 2 + q2;
        const int ipr = 16 * q2 + lr;
#pragma unroll
        for (int ks = 0; ks < 2; ++ks) {
          const int bo = 64 * ks + 16 * lg;
          const int swr = bo ^ ((ipr & 7) << 4);
          const bf16x8 pa = *(const bf16x8*)((const char*)pl + ipr * 128 + swr);
#pragma unroll
          for (int nj = 0; nj < 2; ++nj)
            o[qi][nj] = __builtin_amdgcn_mfma_f32_16x16x32_bf16(pa, vfr[nj][ks].v, o[qi][nj], 0, 0, 0);
        }
      }
    }
  }

  const size_t orow = (size_t)b * NWIN;
#pragma unroll
  for (int qi = 0; qi < 4; ++qi)
#pragma unroll
    for (int r = 0; r < 4; ++r) {
      const int i = 16 * qi + 4 * lg + r;
      if (i < NWIN) {
#pragma unroll
        for (int nj = 0; nj < 2; ++nj)
          aout[(orow + i) * C_DIM + h * HD + 16 * nj + lr] = f32_to_bf16(o[qi][nj][r]);
      }
    }
}

// ---------------------------------------------------------------- launch
static const size_t SZ_QKV = (size_t)M_ROWS * QKV_N * 2;   // 308 MB (blocked layout)
static const size_t SZ_XB  = (size_t)M_ROWS * C_DIM * 2;
static const size_t SZ_WQ  = (size_t)QKV_N * C_DIM * 2;
static const size_t OFF_QKV = 0;
static const size_t OFF_XB  = OFF_QKV + SZ_QKV;   // x_bf16, later attn_out
static const size_t OFF_WQ  = OFF_XB + SZ_XB;
static const size_t OFF_WP  = OFF_WQ + SZ_WQ;

extern "C" void kernel_launch(void* const* d_in, const int* in_sizes, int n_in,
                              void* d_out, int out_size, void* d_ws, size_t ws_size,
                              hipStream_t stream) {
  const float* x      = (const float*)d_in[0];
  const float* mask   = (const float*)d_in[1];
  const float* qkv_w  = (const float*)d_in[2];
  const float* qkv_b  = (const float*)d_in[3];
  const float* proj_w = (const float*)d_in[4];
  const float* proj_b = (const float*)d_in[5];
  const float* rel    = (const float*)d_in[6];
  float* out = (float*)d_out;

  char* ws = (char*)d_ws;
  unsigned short* qkvb = (unsigned short*)(ws + OFF_QKV);
  unsigned short* xb   = (unsigned short*)(ws + OFF_XB);
  unsigned short* wqT  = (unsigned short*)(ws + OFF_WQ);
  unsigned short* wpT  = (unsigned short*)(ws + OFF_WP);
  // bmt (16.78 MB) in d_out scratch: fully consumed by k_attn before final GEMM.
  float* bmt = (float*)d_out;

  k_cvt<<<2048, 256, 0, stream>>>(x, xb, M_ROWS * C_DIM / 4);
  k_transpose_cvt<<<dim3(QKV_N / 32, C_DIM / 32), 256, 0, stream>>>(qkv_w, wqT, C_DIM, QKV_N);
  k_transpose_cvt<<<dim3(C_DIM / 32, C_DIM / 32), 256, 0, stream>>>(proj_w, wpT, C_DIM, C_DIM);
  k_bm<<<(NMASK * NH * 64 * 64) / 256, 256, 0, stream>>>(mask, rel, bmt);

  // qkv = x @ qkv_w + qkv_b  (bf16, blocked layout), grid 6*392 = 2352 (%8==0)
  k_gemm_qkv<<<(QKV_N / 256) * (M_ROWS / 256), 512, 0, stream>>>(
      xb, wqT, qkv_b, qkvb, M_ROWS, QKV_N, C_DIM);

  // attention -> attn_out (reuses xb region), 8192 blocks (%8==0)
  k_attn<<<NMASK * NH * 8, 256, 0, stream>>>(qkvb, bmt, xb);

  // out = attn_out @ proj_w + proj_b  (f32 out), grid 2*392 = 784 (%8==0)
  k_gemm_proj<<<(C_DIM / 256) * (M_ROWS / 256), 512, 0, stream>>>(
      xb, wpT, proj_b, out, M_ROWS, C_DIM, C_DIM);
}